// Round 1
// baseline (1298.335 us; speedup 1.0000x reference)
//
#include <hip/hip_runtime.h>
#include <math.h>

#define FD 128   // feature dim

// ---------------- CSR build ----------------
__global__ void k_count_deg(const int* __restrict__ row, int E, int* __restrict__ deg){
  int i = blockIdx.x * blockDim.x + threadIdx.x;
  int stride = gridDim.x * blockDim.x;
  for (; i < E; i += stride) atomicAdd(&deg[row[i]], 1);
}

__global__ __launch_bounds__(1024) void k_scan_excl(const int* __restrict__ in, int* __restrict__ out, int n){
  __shared__ int tmp[1024];
  __shared__ int carry_s;
  const int tid = threadIdx.x;
  if (tid == 0) carry_s = 0;
  __syncthreads();
  for (int base = 0; base < n; base += 1024){
    int idx = base + tid;
    int v = (idx < n) ? in[idx] : 0;
    tmp[tid] = v;
    __syncthreads();
    for (int off = 1; off < 1024; off <<= 1){
      int t = (tid >= off) ? tmp[tid - off] : 0;
      __syncthreads();
      tmp[tid] += t;
      __syncthreads();
    }
    int carry = carry_s;
    if (idx < n) out[idx] = carry + tmp[tid] - v;
    __syncthreads();
    if (tid == 1023) carry_s = carry + tmp[1023];
    __syncthreads();
  }
  if (tid == 0) out[n] = carry_s;
}

__global__ void k_fill_csr(const int* __restrict__ row, const int* __restrict__ col, int E,
                           const int* __restrict__ rowstart, int* __restrict__ cursor,
                           int* __restrict__ csrcol){
  int i = blockIdx.x * blockDim.x + threadIdx.x;
  int stride = gridDim.x * blockDim.x;
  for (; i < E; i += stride){
    int r = row[i];
    int pos = rowstart[r] + atomicAdd(&cursor[r], 1);
    csrcol[pos] = col[i];
  }
}

// ---------------- GEMM: Y = act(X @ W^T + b) ----------------
// Block: 64 rows x 128 cols, 256 threads, whole K=128 staged in LDS.
template<int ACT>
__global__ __launch_bounds__(256) void k_gemm_xwt(const float* __restrict__ X,
    const float* __restrict__ W, const float* __restrict__ bias,
    float* __restrict__ Y, int ldy, int nrows)
{
  __shared__ float sX[64][132];   // pad 132: rows 16B-aligned, X reads broadcast
  __shared__ float sW[128][132];  // cols spread tc+32j -> 4-way worst on reads
  const int tid = threadIdx.x;
  const int row0 = blockIdx.x * 64;
  for (int i = tid; i < 64 * 32; i += 256){
    int r = i >> 5, c4 = (i & 31) << 2;
    float4 v = make_float4(0.f, 0.f, 0.f, 0.f);
    if (row0 + r < nrows) v = *(const float4*)(X + (size_t)(row0 + r) * FD + c4);
    *(float4*)&sX[r][c4] = v;
  }
  for (int i = tid; i < 128 * 32; i += 256){
    int r = i >> 5, c4 = (i & 31) << 2;
    float4 v = *(const float4*)(W + (size_t)r * FD + c4);
    *(float4*)&sW[r][c4] = v;
  }
  __syncthreads();
  const int tr = tid >> 5;   // rows 8*tr .. 8*tr+7
  const int tc = tid & 31;   // cols tc + 32*j
  float acc[8][4];
  #pragma unroll
  for (int i = 0; i < 8; i++)
    #pragma unroll
    for (int j = 0; j < 4; j++) acc[i][j] = 0.f;
  #pragma unroll 4
  for (int d = 0; d < FD; d += 4){
    float4 xv[8], wv[4];
    #pragma unroll
    for (int i = 0; i < 8; i++) xv[i] = *(const float4*)&sX[8*tr + i][d];
    #pragma unroll
    for (int j = 0; j < 4; j++) wv[j] = *(const float4*)&sW[tc + 32*j][d];
    #pragma unroll
    for (int i = 0; i < 8; i++)
      #pragma unroll
      for (int j = 0; j < 4; j++)
        acc[i][j] += xv[i].x*wv[j].x + xv[i].y*wv[j].y + xv[i].z*wv[j].z + xv[i].w*wv[j].w;
  }
  float bj[4];
  #pragma unroll
  for (int j = 0; j < 4; j++) bj[j] = bias[tc + 32*j];
  #pragma unroll
  for (int i = 0; i < 8; i++){
    int r = row0 + 8*tr + i;
    if (r < nrows){
      #pragma unroll
      for (int j = 0; j < 4; j++){
        float v = acc[i][j] + bj[j];
        if (ACT == 1) v = fmaxf(v, 0.f);
        Y[(size_t)r * ldy + tc + 32*j] = v;
      }
    }
  }
}

// ---------------- per-node edge kernels (1 wave = 1 node, float2/lane) ----------------
__global__ __launch_bounds__(256) void k_scores(const float* __restrict__ Q, const float* __restrict__ K,
    const int* __restrict__ rowstart, const int* __restrict__ csrcol,
    float* __restrict__ scores, int nnodes)
{
  const int n = blockIdx.x * 4 + (threadIdx.x >> 6);
  if (n >= nnodes) return;
  const int lane = threadIdx.x & 63;
  const float2 q = *(const float2*)(Q + (size_t)n * FD + 2*lane);
  const int p0 = rowstart[n], p1 = rowstart[n+1];
  for (int p = p0; p < p1; ++p){
    const int c = csrcol[p];
    const float2 kv = *(const float2*)(K + (size_t)c * FD + 2*lane);
    float d = q.x*kv.x + q.y*kv.y;
    d += __shfl_xor(d, 32, 64);
    d += __shfl_xor(d, 16, 64);
    d += __shfl_xor(d,  8, 64);
    d += __shfl_xor(d,  4, 64);
    d += __shfl_xor(d,  2, 64);
    d += __shfl_xor(d,  1, 64);
    if (lane == 0) scores[p] = d * 0.08838834764831845f;  // 1/sqrt(128)
  }
}

template<int ELU>
__global__ __launch_bounds__(256) void k_message(const float* __restrict__ V, const float* __restrict__ aexp,
    const float* __restrict__ inv_p, const int* __restrict__ rowstart, const int* __restrict__ csrcol,
    float* __restrict__ out, int ldo, int nnodes)
{
  const int n = blockIdx.x * 4 + (threadIdx.x >> 6);
  if (n >= nnodes) return;
  const int lane = threadIdx.x & 63;
  const float inv = inv_p[0];
  float ax = 0.f, ay = 0.f;
  const int p0 = rowstart[n], p1 = rowstart[n+1];
  for (int p = p0; p < p1; ++p){
    const int c = csrcol[p];
    const float a = aexp[p];
    const float2 v = *(const float2*)(V + (size_t)c * FD + 2*lane);
    ax += a * v.x; ay += a * v.y;
  }
  ax *= inv; ay *= inv;
  if (ELU){
    ax = ax > 0.f ? ax : expm1f(ax);
    ay = ay > 0.f ? ay : expm1f(ay);
  }
  *(float2*)(out + (size_t)n * ldo + 2*lane) = make_float2(ax, ay);
}

__global__ __launch_bounds__(256) void k_seg_mean(const float* __restrict__ X,
    const int* __restrict__ rowstart, const int* __restrict__ csrcol,
    float* __restrict__ out, int nnodes)
{
  const int n = blockIdx.x * 4 + (threadIdx.x >> 6);
  if (n >= nnodes) return;
  const int lane = threadIdx.x & 63;
  float ax = 0.f, ay = 0.f;
  const int p0 = rowstart[n], p1 = rowstart[n+1];
  for (int p = p0; p < p1; ++p){
    const int c = csrcol[p];
    const float2 v = *(const float2*)(X + (size_t)c * FD + 2*lane);
    ax += v.x; ay += v.y;
  }
  const int degn = (p1 - p0) > 1 ? (p1 - p0) : 1;
  const float invdeg = 1.f / (float)degn;
  *(float2*)(out + (size_t)n * FD + 2*lane) = make_float2(ax*invdeg, ay*invdeg);
}

// ---------------- softmax reductions ----------------
__global__ __launch_bounds__(256) void k_max_partial(const float* __restrict__ s, int n, float* __restrict__ partial){
  __shared__ float sm[256];
  const int tid = threadIdx.x;
  float m = -3.402823466e38f;
  for (int i = blockIdx.x * 256 + tid; i < n; i += gridDim.x * 256) m = fmaxf(m, s[i]);
  sm[tid] = m; __syncthreads();
  for (int off = 128; off > 0; off >>= 1){
    if (tid < off) sm[tid] = fmaxf(sm[tid], sm[tid + off]);
    __syncthreads();
  }
  if (tid == 0) partial[blockIdx.x] = sm[0];
}

__global__ __launch_bounds__(256) void k_max_final(const float* __restrict__ partial, int n, float* __restrict__ out){
  __shared__ float sm[256];
  const int tid = threadIdx.x;
  float m = -3.402823466e38f;
  for (int i = tid; i < n; i += 256) m = fmaxf(m, partial[i]);
  sm[tid] = m; __syncthreads();
  for (int off = 128; off > 0; off >>= 1){
    if (tid < off) sm[tid] = fmaxf(sm[tid], sm[tid + off]);
    __syncthreads();
  }
  if (tid == 0) out[0] = sm[0];
}

__global__ __launch_bounds__(256) void k_sumexp_partial(float* __restrict__ s, int n,
    const float* __restrict__ smax_p, float* __restrict__ partial){
  __shared__ float sm[256];
  const int tid = threadIdx.x;
  const float m = smax_p[0];
  float acc = 0.f;
  for (int i = blockIdx.x * 256 + tid; i < n; i += gridDim.x * 256){
    float e = expf(s[i] - m);
    s[i] = e;            // overwrite score with exp(s - max)
    acc += e;
  }
  sm[tid] = acc; __syncthreads();
  for (int off = 128; off > 0; off >>= 1){
    if (tid < off) sm[tid] += sm[tid + off];
    __syncthreads();
  }
  if (tid == 0) partial[blockIdx.x] = sm[0];
}

__global__ __launch_bounds__(256) void k_sum_final(const float* __restrict__ partial, int n, float* __restrict__ invout){
  __shared__ float sm[256];
  const int tid = threadIdx.x;
  float acc = 0.f;
  for (int i = tid; i < n; i += 256) acc += partial[i];
  sm[tid] = acc; __syncthreads();
  for (int off = 128; off > 0; off >>= 1){
    if (tid < off) sm[tid] += sm[tid + off];
    __syncthreads();
  }
  if (tid == 0) invout[0] = 1.f / sm[0];
}

extern "C" void kernel_launch(void* const* d_in, const int* in_sizes, int n_in,
                              void* d_out, int out_size, void* d_ws, size_t ws_size,
                              hipStream_t stream)
{
  const float* x   = (const float*)d_in[0];
  const int*   ei  = (const int*)d_in[1];
  const float* Wq1 = (const float*)d_in[2];  const float* bq1 = (const float*)d_in[3];
  const float* Wk1 = (const float*)d_in[4];  const float* bk1 = (const float*)d_in[5];
  const float* Wv1 = (const float*)d_in[6];  const float* bv1 = (const float*)d_in[7];
  const float* Wq2 = (const float*)d_in[8];  const float* bq2 = (const float*)d_in[9];
  const float* Wk2 = (const float*)d_in[10]; const float* bk2 = (const float*)d_in[11];
  const float* Wv2 = (const float*)d_in[12]; const float* bv2 = (const float*)d_in[13];
  const float* Ws1 = (const float*)d_in[14]; const float* bs1 = (const float*)d_in[15];
  const float* Ws2 = (const float*)d_in[16]; const float* bs2 = (const float*)d_in[17];

  const int N = in_sizes[0] / FD;
  const int E = in_sizes[1] / 2;
  const int* row = ei;
  const int* col = ei + E;
  float* out = (float*)d_out;

  char* ws = (char*)d_ws;
  size_t off = 0;
  auto alloc = [&](size_t bytes) -> void* {
    void* p = ws + off;
    off += (bytes + 255) & ~(size_t)255;
    return p;
  };
  int* deg      = (int*)alloc((size_t)N * 4);
  int* rowstart = (int*)alloc((size_t)(N + 1) * 4);
  int* cursor   = (int*)alloc((size_t)N * 4);
  int* csrcol   = (int*)alloc((size_t)E * 4);
  float* scores = (float*)alloc((size_t)E * 4);
  float* partial = (float*)alloc(1024);
  float* smax_p  = (float*)alloc(256);
  float* isum_p  = (float*)alloc(256);
  float* A = (float*)alloc((size_t)N * FD * 4);
  float* B = (float*)alloc((size_t)N * FD * 4);
  float* C = (float*)alloc((size_t)N * FD * 4);
  (void)ws_size; (void)n_in; (void)out_size;

  hipMemsetAsync(deg, 0, (size_t)N * 4, stream);
  hipMemsetAsync(cursor, 0, (size_t)N * 4, stream);

  const int eb = 2048;            // edge kernel blocks (grid-stride)
  k_count_deg<<<eb, 256, 0, stream>>>(row, E, deg);
  k_scan_excl<<<1, 1024, 0, stream>>>(deg, rowstart, N);
  k_fill_csr<<<eb, 256, 0, stream>>>(row, col, E, rowstart, cursor, csrcol);

  const int gb = (N + 63) / 64;   // gemm blocks
  const int nb = (N + 3) / 4;     // node-wave blocks (4 nodes/block)
  const int rb = 256;             // reduction partial blocks

  // ---- attention layer 1 ----
  k_gemm_xwt<0><<<gb, 256, 0, stream>>>(x, Wq1, bq1, A, FD, N);
  k_gemm_xwt<0><<<gb, 256, 0, stream>>>(x, Wk1, bk1, B, FD, N);
  k_gemm_xwt<0><<<gb, 256, 0, stream>>>(x, Wv1, bv1, C, FD, N);
  k_scores<<<nb, 256, 0, stream>>>(A, B, rowstart, csrcol, scores, N);
  k_max_partial<<<rb, 256, 0, stream>>>(scores, E, partial);
  k_max_final<<<1, 256, 0, stream>>>(partial, rb, smax_p);
  k_sumexp_partial<<<rb, 256, 0, stream>>>(scores, E, smax_p, partial);
  k_sum_final<<<1, 256, 0, stream>>>(partial, rb, isum_p);
  k_message<1><<<nb, 256, 0, stream>>>(C, scores, isum_p, rowstart, csrcol, A, FD, N); // h=elu(.) -> A

  // ---- attention layer 2 ----
  k_gemm_xwt<0><<<gb, 256, 0, stream>>>(A, Wq2, bq2, B, FD, N);
  k_gemm_xwt<0><<<gb, 256, 0, stream>>>(A, Wk2, bk2, C, FD, N);
  k_scores<<<nb, 256, 0, stream>>>(B, C, rowstart, csrcol, scores, N);
  k_max_partial<<<rb, 256, 0, stream>>>(scores, E, partial);
  k_max_final<<<1, 256, 0, stream>>>(partial, rb, smax_p);
  k_sumexp_partial<<<rb, 256, 0, stream>>>(scores, E, smax_p, partial);
  k_sum_final<<<1, 256, 0, stream>>>(partial, rb, isum_p);
  k_gemm_xwt<0><<<gb, 256, 0, stream>>>(A, Wv2, bv2, B, FD, N);   // V2 -> B
  k_message<0><<<nb, 256, 0, stream>>>(B, scores, isum_p, rowstart, csrcol, out, 2*FD, N);

  // ---- secondary structure path ----
  k_seg_mean<<<nb, 256, 0, stream>>>(x, rowstart, csrcol, A, N);
  k_gemm_xwt<1><<<gb, 256, 0, stream>>>(A, Ws1, bs1, B, FD, N);
  k_seg_mean<<<nb, 256, 0, stream>>>(B, rowstart, csrcol, A, N);
  k_gemm_xwt<1><<<gb, 256, 0, stream>>>(A, Ws2, bs2, out + FD, 2*FD, N);
}

// Round 2
// 1100.410 us; speedup vs baseline: 1.1799x; 1.1799x over previous
//
#include <hip/hip_runtime.h>
#include <math.h>

#define FD 128   // feature dim

// ---------------- CSR build ----------------
__global__ void k_count_deg(const int* __restrict__ row, int E, int* __restrict__ deg){
  int i = blockIdx.x * blockDim.x + threadIdx.x;
  int stride = gridDim.x * blockDim.x;
  for (; i < E; i += stride) atomicAdd(&deg[row[i]], 1);
}

__global__ __launch_bounds__(1024) void k_scan_excl(const int* __restrict__ in, int* __restrict__ out, int n){
  __shared__ int tmp[1024];
  __shared__ int carry_s;
  const int tid = threadIdx.x;
  if (tid == 0) carry_s = 0;
  __syncthreads();
  for (int base = 0; base < n; base += 1024){
    int idx = base + tid;
    int v = (idx < n) ? in[idx] : 0;
    tmp[tid] = v;
    __syncthreads();
    for (int off = 1; off < 1024; off <<= 1){
      int t = (tid >= off) ? tmp[tid - off] : 0;
      __syncthreads();
      tmp[tid] += t;
      __syncthreads();
    }
    int carry = carry_s;
    if (idx < n) out[idx] = carry + tmp[tid] - v;
    __syncthreads();
    if (tid == 1023) carry_s = carry + tmp[1023];
    __syncthreads();
  }
  if (tid == 0) out[n] = carry_s;
}

__global__ void k_fill_csr(const int* __restrict__ row, const int* __restrict__ col, int E,
                           const int* __restrict__ rowstart, int* __restrict__ cursor,
                           int* __restrict__ csrcol){
  int i = blockIdx.x * blockDim.x + threadIdx.x;
  int stride = gridDim.x * blockDim.x;
  for (; i < E; i += stride){
    int r = row[i];
    int pos = rowstart[r] + atomicAdd(&cursor[r], 1);
    csrcol[pos] = col[i];
  }
}

// ---------------- GEMM: Y = act(X @ W^T + b) ----------------
// Block: 64 rows x 128 cols, 256 threads, whole K=128 staged in LDS.
template<int ACT>
__global__ __launch_bounds__(256) void k_gemm_xwt(const float* __restrict__ X, int ldx,
    const float* __restrict__ W, const float* __restrict__ bias,
    float* __restrict__ Y, int ldy, int nrows)
{
  __shared__ float sX[64][132];
  __shared__ float sW[128][132];
  const int tid = threadIdx.x;
  const int row0 = blockIdx.x * 64;
  for (int i = tid; i < 64 * 32; i += 256){
    int r = i >> 5, c4 = (i & 31) << 2;
    float4 v = make_float4(0.f, 0.f, 0.f, 0.f);
    if (row0 + r < nrows) v = *(const float4*)(X + (size_t)(row0 + r) * ldx + c4);
    *(float4*)&sX[r][c4] = v;
  }
  for (int i = tid; i < 128 * 32; i += 256){
    int r = i >> 5, c4 = (i & 31) << 2;
    float4 v = *(const float4*)(W + (size_t)r * FD + c4);
    *(float4*)&sW[r][c4] = v;
  }
  __syncthreads();
  const int tr = tid >> 5;
  const int tc = tid & 31;
  float acc[8][4];
  #pragma unroll
  for (int i = 0; i < 8; i++)
    #pragma unroll
    for (int j = 0; j < 4; j++) acc[i][j] = 0.f;
  #pragma unroll 4
  for (int d = 0; d < FD; d += 4){
    float4 xv[8], wv[4];
    #pragma unroll
    for (int i = 0; i < 8; i++) xv[i] = *(const float4*)&sX[8*tr + i][d];
    #pragma unroll
    for (int j = 0; j < 4; j++) wv[j] = *(const float4*)&sW[tc + 32*j][d];
    #pragma unroll
    for (int i = 0; i < 8; i++)
      #pragma unroll
      for (int j = 0; j < 4; j++)
        acc[i][j] += xv[i].x*wv[j].x + xv[i].y*wv[j].y + xv[i].z*wv[j].z + xv[i].w*wv[j].w;
  }
  float bj[4];
  #pragma unroll
  for (int j = 0; j < 4; j++) bj[j] = bias[tc + 32*j];
  #pragma unroll
  for (int i = 0; i < 8; i++){
    int r = row0 + 8*tr + i;
    if (r < nrows){
      #pragma unroll
      for (int j = 0; j < 4; j++){
        float v = acc[i][j] + bj[j];
        if (ACT == 1) v = fmaxf(v, 0.f);
        Y[(size_t)r * ldy + tc + 32*j] = v;
      }
    }
  }
}

// ---------------- fused edge passes (1 wave = 1 node, float2/lane, unroll x4) ----------------

#define WAVE_REDUCE6(d) \
  d += __shfl_xor(d, 32, 64); d += __shfl_xor(d, 16, 64); d += __shfl_xor(d, 8, 64); \
  d += __shfl_xor(d, 4, 64);  d += __shfl_xor(d, 2, 64);  d += __shfl_xor(d, 1, 64);

// scores (Q.K per edge) fused with segment-mean of X
__global__ __launch_bounds__(256) void k_passA(const float* __restrict__ Q, const float* __restrict__ K,
    const float* __restrict__ X, const int* __restrict__ rowstart, const int* __restrict__ csrcol,
    float* __restrict__ scores, float* __restrict__ segout, int ldseg, int nnodes)
{
  const int n = blockIdx.x * 4 + (threadIdx.x >> 6);
  if (n >= nnodes) return;
  const int lane = threadIdx.x & 63;
  const float2 q = *(const float2*)(Q + (unsigned)n * FD + 2*lane);
  float sx = 0.f, sy = 0.f;
  const int p0 = rowstart[n], p1 = rowstart[n+1];
  int p = p0;
  for (; p + 3 < p1; p += 4){
    const int c0 = csrcol[p], c1 = csrcol[p+1], c2 = csrcol[p+2], c3 = csrcol[p+3];
    const float2 k0 = *(const float2*)(K + (unsigned)c0 * FD + 2*lane);
    const float2 k1 = *(const float2*)(K + (unsigned)c1 * FD + 2*lane);
    const float2 k2 = *(const float2*)(K + (unsigned)c2 * FD + 2*lane);
    const float2 k3 = *(const float2*)(K + (unsigned)c3 * FD + 2*lane);
    const float2 x0 = *(const float2*)(X + (unsigned)c0 * FD + 2*lane);
    const float2 x1 = *(const float2*)(X + (unsigned)c1 * FD + 2*lane);
    const float2 x2 = *(const float2*)(X + (unsigned)c2 * FD + 2*lane);
    const float2 x3 = *(const float2*)(X + (unsigned)c3 * FD + 2*lane);
    float d0 = q.x*k0.x + q.y*k0.y;
    float d1 = q.x*k1.x + q.y*k1.y;
    float d2 = q.x*k2.x + q.y*k2.y;
    float d3 = q.x*k3.x + q.y*k3.y;
    sx += x0.x + x1.x + x2.x + x3.x;
    sy += x0.y + x1.y + x2.y + x3.y;
    WAVE_REDUCE6(d0) WAVE_REDUCE6(d1) WAVE_REDUCE6(d2) WAVE_REDUCE6(d3)
    const float sv = (lane == 0) ? d0 : (lane == 1) ? d1 : (lane == 2) ? d2 : d3;
    if (lane < 4) scores[p + lane] = sv * 0.08838834764831845f;
  }
  for (; p < p1; ++p){
    const int c = csrcol[p];
    const float2 kv = *(const float2*)(K + (unsigned)c * FD + 2*lane);
    const float2 xv = *(const float2*)(X + (unsigned)c * FD + 2*lane);
    float d = q.x*kv.x + q.y*kv.y;
    sx += xv.x; sy += xv.y;
    WAVE_REDUCE6(d)
    if (lane == 0) scores[p] = d * 0.08838834764831845f;
  }
  const int degn = (p1 - p0) > 1 ? (p1 - p0) : 1;
  const float invdeg = 1.f / (float)degn;
  *(float2*)(segout + (unsigned)n * ldseg + 2*lane) = make_float2(sx*invdeg, sy*invdeg);
}

// message (alpha-weighted V aggregate, ELU) fused with segment-mean of SM
__global__ __launch_bounds__(256) void k_passB(const float* __restrict__ V, const float* __restrict__ SM,
    int ldsm, const float* __restrict__ aexp, const float* __restrict__ inv_p,
    const int* __restrict__ rowstart, const int* __restrict__ csrcol,
    float* __restrict__ hout, float* __restrict__ segout, int nnodes)
{
  const int n = blockIdx.x * 4 + (threadIdx.x >> 6);
  if (n >= nnodes) return;
  const int lane = threadIdx.x & 63;
  const float inv = inv_p[0];
  float ax = 0.f, ay = 0.f, sx = 0.f, sy = 0.f;
  const int p0 = rowstart[n], p1 = rowstart[n+1];
  int p = p0;
  for (; p + 3 < p1; p += 4){
    const int c0 = csrcol[p], c1 = csrcol[p+1], c2 = csrcol[p+2], c3 = csrcol[p+3];
    const float a0 = aexp[p], a1 = aexp[p+1], a2 = aexp[p+2], a3 = aexp[p+3];
    const float2 v0 = *(const float2*)(V + (unsigned)c0 * FD + 2*lane);
    const float2 v1 = *(const float2*)(V + (unsigned)c1 * FD + 2*lane);
    const float2 v2 = *(const float2*)(V + (unsigned)c2 * FD + 2*lane);
    const float2 v3 = *(const float2*)(V + (unsigned)c3 * FD + 2*lane);
    const float2 s0 = *(const float2*)(SM + (unsigned)c0 * ldsm + 2*lane);
    const float2 s1 = *(const float2*)(SM + (unsigned)c1 * ldsm + 2*lane);
    const float2 s2 = *(const float2*)(SM + (unsigned)c2 * ldsm + 2*lane);
    const float2 s3 = *(const float2*)(SM + (unsigned)c3 * ldsm + 2*lane);
    ax += a0*v0.x + a1*v1.x + a2*v2.x + a3*v3.x;
    ay += a0*v0.y + a1*v1.y + a2*v2.y + a3*v3.y;
    sx += s0.x + s1.x + s2.x + s3.x;
    sy += s0.y + s1.y + s2.y + s3.y;
  }
  for (; p < p1; ++p){
    const int c = csrcol[p];
    const float a = aexp[p];
    const float2 v = *(const float2*)(V + (unsigned)c * FD + 2*lane);
    const float2 s = *(const float2*)(SM + (unsigned)c * ldsm + 2*lane);
    ax += a*v.x; ay += a*v.y;
    sx += s.x;   sy += s.y;
  }
  ax *= inv; ay *= inv;
  ax = ax > 0.f ? ax : expm1f(ax);
  ay = ay > 0.f ? ay : expm1f(ay);
  *(float2*)(hout + (unsigned)n * FD + 2*lane) = make_float2(ax, ay);
  const int degn = (p1 - p0) > 1 ? (p1 - p0) : 1;
  const float invdeg = 1.f / (float)degn;
  *(float2*)(segout + (unsigned)n * FD + 2*lane) = make_float2(sx*invdeg, sy*invdeg);
}

// plain scores, unroll x4
__global__ __launch_bounds__(256) void k_scores(const float* __restrict__ Q, const float* __restrict__ K,
    const int* __restrict__ rowstart, const int* __restrict__ csrcol,
    float* __restrict__ scores, int nnodes)
{
  const int n = blockIdx.x * 4 + (threadIdx.x >> 6);
  if (n >= nnodes) return;
  const int lane = threadIdx.x & 63;
  const float2 q = *(const float2*)(Q + (unsigned)n * FD + 2*lane);
  const int p0 = rowstart[n], p1 = rowstart[n+1];
  int p = p0;
  for (; p + 3 < p1; p += 4){
    const int c0 = csrcol[p], c1 = csrcol[p+1], c2 = csrcol[p+2], c3 = csrcol[p+3];
    const float2 k0 = *(const float2*)(K + (unsigned)c0 * FD + 2*lane);
    const float2 k1 = *(const float2*)(K + (unsigned)c1 * FD + 2*lane);
    const float2 k2 = *(const float2*)(K + (unsigned)c2 * FD + 2*lane);
    const float2 k3 = *(const float2*)(K + (unsigned)c3 * FD + 2*lane);
    float d0 = q.x*k0.x + q.y*k0.y;
    float d1 = q.x*k1.x + q.y*k1.y;
    float d2 = q.x*k2.x + q.y*k2.y;
    float d3 = q.x*k3.x + q.y*k3.y;
    WAVE_REDUCE6(d0) WAVE_REDUCE6(d1) WAVE_REDUCE6(d2) WAVE_REDUCE6(d3)
    const float sv = (lane == 0) ? d0 : (lane == 1) ? d1 : (lane == 2) ? d2 : d3;
    if (lane < 4) scores[p + lane] = sv * 0.08838834764831845f;
  }
  for (; p < p1; ++p){
    const int c = csrcol[p];
    const float2 kv = *(const float2*)(K + (unsigned)c * FD + 2*lane);
    float d = q.x*kv.x + q.y*kv.y;
    WAVE_REDUCE6(d)
    if (lane == 0) scores[p] = d * 0.08838834764831845f;
  }
}

// plain message (no ELU), unroll x4
__global__ __launch_bounds__(256) void k_message(const float* __restrict__ V, const float* __restrict__ aexp,
    const float* __restrict__ inv_p, const int* __restrict__ rowstart, const int* __restrict__ csrcol,
    float* __restrict__ out, int ldo, int nnodes)
{
  const int n = blockIdx.x * 4 + (threadIdx.x >> 6);
  if (n >= nnodes) return;
  const int lane = threadIdx.x & 63;
  const float inv = inv_p[0];
  float ax = 0.f, ay = 0.f;
  const int p0 = rowstart[n], p1 = rowstart[n+1];
  int p = p0;
  for (; p + 3 < p1; p += 4){
    const int c0 = csrcol[p], c1 = csrcol[p+1], c2 = csrcol[p+2], c3 = csrcol[p+3];
    const float a0 = aexp[p], a1 = aexp[p+1], a2 = aexp[p+2], a3 = aexp[p+3];
    const float2 v0 = *(const float2*)(V + (unsigned)c0 * FD + 2*lane);
    const float2 v1 = *(const float2*)(V + (unsigned)c1 * FD + 2*lane);
    const float2 v2 = *(const float2*)(V + (unsigned)c2 * FD + 2*lane);
    const float2 v3 = *(const float2*)(V + (unsigned)c3 * FD + 2*lane);
    ax += a0*v0.x + a1*v1.x + a2*v2.x + a3*v3.x;
    ay += a0*v0.y + a1*v1.y + a2*v2.y + a3*v3.y;
  }
  for (; p < p1; ++p){
    const int c = csrcol[p];
    const float a = aexp[p];
    const float2 v = *(const float2*)(V + (unsigned)c * FD + 2*lane);
    ax += a*v.x; ay += a*v.y;
  }
  *(float2*)(out + (unsigned)n * ldo + 2*lane) = make_float2(ax*inv, ay*inv);
}

// ---------------- softmax reductions ----------------
__global__ __launch_bounds__(256) void k_max_partial(const float* __restrict__ s, int n, float* __restrict__ partial){
  __shared__ float sm[256];
  const int tid = threadIdx.x;
  float m = -3.402823466e38f;
  for (int i = blockIdx.x * 256 + tid; i < n; i += gridDim.x * 256) m = fmaxf(m, s[i]);
  sm[tid] = m; __syncthreads();
  for (int off = 128; off > 0; off >>= 1){
    if (tid < off) sm[tid] = fmaxf(sm[tid], sm[tid + off]);
    __syncthreads();
  }
  if (tid == 0) partial[blockIdx.x] = sm[0];
}

__global__ __launch_bounds__(256) void k_max_final(const float* __restrict__ partial, int n, float* __restrict__ out){
  __shared__ float sm[256];
  const int tid = threadIdx.x;
  float m = -3.402823466e38f;
  for (int i = tid; i < n; i += 256) m = fmaxf(m, partial[i]);
  sm[tid] = m; __syncthreads();
  for (int off = 128; off > 0; off >>= 1){
    if (tid < off) sm[tid] = fmaxf(sm[tid], sm[tid + off]);
    __syncthreads();
  }
  if (tid == 0) out[0] = sm[0];
}

__global__ __launch_bounds__(256) void k_sumexp_partial(float* __restrict__ s, int n,
    const float* __restrict__ smax_p, float* __restrict__ partial){
  __shared__ float sm[256];
  const int tid = threadIdx.x;
  const float m = smax_p[0];
  float acc = 0.f;
  for (int i = blockIdx.x * 256 + tid; i < n; i += gridDim.x * 256){
    float e = expf(s[i] - m);
    s[i] = e;
    acc += e;
  }
  sm[tid] = acc; __syncthreads();
  for (int off = 128; off > 0; off >>= 1){
    if (tid < off) sm[tid] += sm[tid + off];
    __syncthreads();
  }
  if (tid == 0) partial[blockIdx.x] = sm[0];
}

__global__ __launch_bounds__(256) void k_sum_final(const float* __restrict__ partial, int n, float* __restrict__ invout){
  __shared__ float sm[256];
  const int tid = threadIdx.x;
  float acc = 0.f;
  for (int i = tid; i < n; i += 256) acc += partial[i];
  sm[tid] = acc; __syncthreads();
  for (int off = 128; off > 0; off >>= 1){
    if (tid < off) sm[tid] += sm[tid + off];
    __syncthreads();
  }
  if (tid == 0) invout[0] = 1.f / sm[0];
}

extern "C" void kernel_launch(void* const* d_in, const int* in_sizes, int n_in,
                              void* d_out, int out_size, void* d_ws, size_t ws_size,
                              hipStream_t stream)
{
  const float* x   = (const float*)d_in[0];
  const int*   ei  = (const int*)d_in[1];
  const float* Wq1 = (const float*)d_in[2];  const float* bq1 = (const float*)d_in[3];
  const float* Wk1 = (const float*)d_in[4];  const float* bk1 = (const float*)d_in[5];
  const float* Wv1 = (const float*)d_in[6];  const float* bv1 = (const float*)d_in[7];
  const float* Wq2 = (const float*)d_in[8];  const float* bq2 = (const float*)d_in[9];
  const float* Wk2 = (const float*)d_in[10]; const float* bk2 = (const float*)d_in[11];
  const float* Wv2 = (const float*)d_in[12]; const float* bv2 = (const float*)d_in[13];
  const float* Ws1 = (const float*)d_in[14]; const float* bs1 = (const float*)d_in[15];
  const float* Ws2 = (const float*)d_in[16]; const float* bs2 = (const float*)d_in[17];

  const int N = in_sizes[0] / FD;
  const int E = in_sizes[1] / 2;
  const int* row = ei;
  const int* col = ei + E;
  float* out = (float*)d_out;

  char* ws = (char*)d_ws;
  size_t off = 0;
  auto alloc = [&](size_t bytes) -> void* {
    void* p = ws + off;
    off += (bytes + 255) & ~(size_t)255;
    return p;
  };
  int* deg      = (int*)alloc((size_t)N * 4);
  int* rowstart = (int*)alloc((size_t)(N + 1) * 4);
  int* cursor   = (int*)alloc((size_t)N * 4);
  int* csrcol   = (int*)alloc((size_t)E * 4);
  float* scores = (float*)alloc((size_t)E * 4);
  float* partial = (float*)alloc(1024);
  float* smax_p  = (float*)alloc(256);
  float* isum_p  = (float*)alloc(256);
  float* A = (float*)alloc((size_t)N * FD * 4);
  float* B = (float*)alloc((size_t)N * FD * 4);
  float* C = (float*)alloc((size_t)N * FD * 4);
  (void)ws_size; (void)n_in; (void)out_size;

  hipMemsetAsync(deg, 0, (size_t)N * 4, stream);
  hipMemsetAsync(cursor, 0, (size_t)N * 4, stream);

  const int eb = 2048;
  k_count_deg<<<eb, 256, 0, stream>>>(row, E, deg);
  k_scan_excl<<<1, 1024, 0, stream>>>(deg, rowstart, N);
  k_fill_csr<<<eb, 256, 0, stream>>>(row, col, E, rowstart, cursor, csrcol);

  const int gb = (N + 63) / 64;
  const int nb = (N + 3) / 4;
  const int rb = 256;

  // SM = seg-mean scratch living in out's bpp half (ld 256), overwritten by message2 at the end
  float* SM = out;             // [N,128] with row stride 256

  // ---- layer-1 QKV ----
  k_gemm_xwt<0><<<gb, 256, 0, stream>>>(x, FD, Wq1, bq1, A, FD, N);
  k_gemm_xwt<0><<<gb, 256, 0, stream>>>(x, FD, Wk1, bk1, B, FD, N);
  k_gemm_xwt<0><<<gb, 256, 0, stream>>>(x, FD, Wv1, bv1, C, FD, N);

  // ---- fused: scores1 + seg_mean(x) -> SM ----
  k_passA<<<nb, 256, 0, stream>>>(A, B, x, rowstart, csrcol, scores, SM, 2*FD, N);

  // softmax over all edges
  k_max_partial<<<rb, 256, 0, stream>>>(scores, E, partial);
  k_max_final<<<1, 256, 0, stream>>>(partial, rb, smax_p);
  k_sumexp_partial<<<rb, 256, 0, stream>>>(scores, E, smax_p, partial);
  k_sum_final<<<1, 256, 0, stream>>>(partial, rb, isum_p);

  // s1 = relu(SM @ Ws1^T + bs1), in place (ld 256)
  k_gemm_xwt<1><<<gb, 256, 0, stream>>>(SM, 2*FD, Ws1, bs1, SM, 2*FD, N);

  // ---- fused: message1(V=C)+ELU -> A(h); seg_mean(s1=SM) -> B ----
  k_passB<<<nb, 256, 0, stream>>>(C, SM, 2*FD, scores, isum_p, rowstart, csrcol, A, B, N);

  // ss_out = relu(B @ Ws2^T + bs2) -> out cols [128,256)
  k_gemm_xwt<1><<<gb, 256, 0, stream>>>(B, FD, Ws2, bs2, out + FD, 2*FD, N);

  // ---- layer-2 QK ----
  k_gemm_xwt<0><<<gb, 256, 0, stream>>>(A, FD, Wq2, bq2, C, FD, N);   // Q2 -> C
  k_gemm_xwt<0><<<gb, 256, 0, stream>>>(A, FD, Wk2, bk2, B, FD, N);   // K2 -> B
  k_scores<<<nb, 256, 0, stream>>>(C, B, rowstart, csrcol, scores, N);

  k_max_partial<<<rb, 256, 0, stream>>>(scores, E, partial);
  k_max_final<<<1, 256, 0, stream>>>(partial, rb, smax_p);
  k_sumexp_partial<<<rb, 256, 0, stream>>>(scores, E, smax_p, partial);
  k_sum_final<<<1, 256, 0, stream>>>(partial, rb, isum_p);

  // V2 = A @ Wv2 -> C (Q2 dead after scores2)
  k_gemm_xwt<0><<<gb, 256, 0, stream>>>(A, FD, Wv2, bv2, C, FD, N);
  // message2 -> out cols [0,128)
  k_message<<<nb, 256, 0, stream>>>(C, scores, isum_p, rowstart, csrcol, out, 2*FD, N);
}

// Round 3
// 738.016 us; speedup vs baseline: 1.7592x; 1.4910x over previous
//
#include <hip/hip_runtime.h>
#include <math.h>

#define FD 128

static __device__ __forceinline__ float bf2f(unsigned short u){
  return __uint_as_float(((unsigned int)u) << 16);
}
static __device__ __forceinline__ unsigned short f2bf(float f){
  unsigned int x = __float_as_uint(f);
  x += 0x7fff + ((x >> 16) & 1);   // RNE
  return (unsigned short)(x >> 16);
}

// ---------------- CSR build ----------------
__global__ void k_count_deg(const int* __restrict__ row, int E, int* __restrict__ deg){
  int i = blockIdx.x * blockDim.x + threadIdx.x;
  int stride = gridDim.x * blockDim.x;
  for (; i < E; i += stride) atomicAdd(&deg[row[i]], 1);
}

__global__ __launch_bounds__(1024) void k_scan_excl(const int* __restrict__ in, int* __restrict__ out, int n){
  __shared__ int tmp[1024];
  __shared__ int carry_s;
  const int tid = threadIdx.x;
  if (tid == 0) carry_s = 0;
  __syncthreads();
  for (int base = 0; base < n; base += 1024){
    int idx = base + tid;
    int v = (idx < n) ? in[idx] : 0;
    tmp[tid] = v;
    __syncthreads();
    for (int off = 1; off < 1024; off <<= 1){
      int t = (tid >= off) ? tmp[tid - off] : 0;
      __syncthreads();
      tmp[tid] += t;
      __syncthreads();
    }
    int carry = carry_s;
    if (idx < n) out[idx] = carry + tmp[tid] - v;
    __syncthreads();
    if (tid == 1023) carry_s = carry + tmp[1023];
    __syncthreads();
  }
  if (tid == 0) out[n] = carry_s;
}

__global__ void k_fill_csr(const int* __restrict__ row, const int* __restrict__ col, int E,
                           const int* __restrict__ rowstart, int* __restrict__ cursor,
                           int* __restrict__ csrcol){
  int i = blockIdx.x * blockDim.x + threadIdx.x;
  int stride = gridDim.x * blockDim.x;
  for (; i < E; i += stride){
    int r = row[i];
    int pos = rowstart[r] + atomicAdd(&cursor[r], 1);
    csrcol[pos] = col[i];
  }
}

// ---------------- GEMM: Y = act(X @ W^T + b), K split in 2 phases, 52KB LDS -> 3 blocks/CU
template<int ACT, int OUTBF>
__global__ __launch_bounds__(256) void k_gemm(const float* __restrict__ X, int ldx,
    const float* __restrict__ W, const float* __restrict__ bias,
    void* __restrict__ Y, int ldy, int nrows)
{
  __shared__ float sX[64][68];
  __shared__ float sW[128][68];
  const int tid = threadIdx.x;
  const int row0 = blockIdx.x * 64;
  const int tr = tid >> 5;
  const int tc = tid & 31;
  float acc[8][4];
  #pragma unroll
  for (int i = 0; i < 8; i++)
    #pragma unroll
    for (int j = 0; j < 4; j++) acc[i][j] = 0.f;

  for (int kk = 0; kk < FD; kk += 64){
    for (int i = tid; i < 64 * 16; i += 256){
      int r = i >> 4, c4 = (i & 15) << 2;
      float4 v = make_float4(0.f, 0.f, 0.f, 0.f);
      if (row0 + r < nrows) v = *(const float4*)(X + (size_t)(row0 + r) * ldx + kk + c4);
      *(float4*)&sX[r][c4] = v;
    }
    for (int i = tid; i < 128 * 16; i += 256){
      int r = i >> 4, c4 = (i & 15) << 2;
      *(float4*)&sW[r][c4] = *(const float4*)(W + (size_t)r * FD + kk + c4);
    }
    __syncthreads();
    #pragma unroll 4
    for (int d = 0; d < 64; d += 4){
      float4 xv[8], wv[4];
      #pragma unroll
      for (int i = 0; i < 8; i++) xv[i] = *(const float4*)&sX[8*tr + i][d];
      #pragma unroll
      for (int j = 0; j < 4; j++) wv[j] = *(const float4*)&sW[tc + 32*j][d];
      #pragma unroll
      for (int i = 0; i < 8; i++)
        #pragma unroll
        for (int j = 0; j < 4; j++)
          acc[i][j] += xv[i].x*wv[j].x + xv[i].y*wv[j].y + xv[i].z*wv[j].z + xv[i].w*wv[j].w;
    }
    __syncthreads();
  }
  float bj[4];
  #pragma unroll
  for (int j = 0; j < 4; j++) bj[j] = bias[tc + 32*j];
  #pragma unroll
  for (int i = 0; i < 8; i++){
    int r = row0 + 8*tr + i;
    if (r < nrows){
      #pragma unroll
      for (int j = 0; j < 4; j++){
        float v = acc[i][j] + bj[j];
        if (ACT == 1) v = fmaxf(v, 0.f);
        if (OUTBF) ((unsigned short*)Y)[(size_t)r * ldy + tc + 32*j] = f2bf(v);
        else       ((float*)Y)[(size_t)r * ldy + tc + 32*j] = v;
      }
    }
  }
}

// ---------------- edge passes: 1 wave = 1 node, 32 lanes per row, 2 edges/wave, x4 unroll ----
#define RED5(d) \
  d += __shfl_xor(d, 16, 64); d += __shfl_xor(d, 8, 64); \
  d += __shfl_xor(d,  4, 64); d += __shfl_xor(d, 2, 64); d += __shfl_xor(d, 1, 64);

#define SC 0.08838834764831845f

static __device__ __forceinline__ float dotbf(float4 q, ushort4 k){
  return q.x*bf2f(k.x) + q.y*bf2f(k.y) + q.z*bf2f(k.z) + q.w*bf2f(k.w);
}

// scores1 (Qb.Kb per edge) fused with segment-mean of X (fp32)
__global__ __launch_bounds__(256) void k_passA(const ushort4* __restrict__ Qb, const ushort4* __restrict__ Kb,
    const float4* __restrict__ X, const int* __restrict__ rowstart, const int* __restrict__ csrcol,
    float* __restrict__ scores, float4* __restrict__ segout, int ldseg4, int nnodes)
{
  const int n = blockIdx.x * 4 + (threadIdx.x >> 6);
  if (n >= nnodes) return;
  const int lane = threadIdx.x & 63;
  const int l5 = lane & 31;
  const int h  = lane >> 5;
  ushort4 qu = Qb[(unsigned)n * 32 + l5];
  const float4 q = make_float4(bf2f(qu.x), bf2f(qu.y), bf2f(qu.z), bf2f(qu.w));
  float4 sx = make_float4(0.f, 0.f, 0.f, 0.f);
  const int p0 = rowstart[n], p1 = rowstart[n+1];
  int p = p0;
  for (; p + 8 <= p1; p += 8){
    const int c0 = csrcol[p     + h], c1 = csrcol[p + 2 + h];
    const int c2 = csrcol[p + 4 + h], c3 = csrcol[p + 6 + h];
    ushort4 k0 = Kb[(unsigned)c0*32 + l5], k1 = Kb[(unsigned)c1*32 + l5];
    ushort4 k2 = Kb[(unsigned)c2*32 + l5], k3 = Kb[(unsigned)c3*32 + l5];
    float4 x0 = X[(unsigned)c0*32 + l5], x1 = X[(unsigned)c1*32 + l5];
    float4 x2 = X[(unsigned)c2*32 + l5], x3 = X[(unsigned)c3*32 + l5];
    float d0 = dotbf(q, k0), d1 = dotbf(q, k1), d2 = dotbf(q, k2), d3 = dotbf(q, k3);
    sx.x += x0.x + x1.x + x2.x + x3.x;
    sx.y += x0.y + x1.y + x2.y + x3.y;
    sx.z += x0.z + x1.z + x2.z + x3.z;
    sx.w += x0.w + x1.w + x2.w + x3.w;
    RED5(d0) RED5(d1) RED5(d2) RED5(d3)
    if (l5 == 0){
      scores[p     + h] = d0 * SC;
      scores[p + 2 + h] = d1 * SC;
      scores[p + 4 + h] = d2 * SC;
      scores[p + 6 + h] = d3 * SC;
    }
  }
  for (; p < p1; p += 2){
    const int idx = p + h;
    const bool valid = idx < p1;
    const int c = csrcol[valid ? idx : p];
    ushort4 ku = Kb[(unsigned)c*32 + l5];
    float4 xv = X[(unsigned)c*32 + l5];
    float d = dotbf(q, ku);
    if (valid){ sx.x += xv.x; sx.y += xv.y; sx.z += xv.z; sx.w += xv.w; }
    RED5(d)
    if (valid && l5 == 0) scores[idx] = d * SC;
  }
  sx.x += __shfl_xor(sx.x, 32, 64);
  sx.y += __shfl_xor(sx.y, 32, 64);
  sx.z += __shfl_xor(sx.z, 32, 64);
  sx.w += __shfl_xor(sx.w, 32, 64);
  int dg = p1 - p0; if (dg < 1) dg = 1;
  const float inv = 1.f / (float)dg;
  if (h == 0)
    segout[(unsigned)n * ldseg4 + l5] = make_float4(sx.x*inv, sx.y*inv, sx.z*inv, sx.w*inv);
}

// plain scores (layer 2)
__global__ __launch_bounds__(256) void k_scores2(const ushort4* __restrict__ Qb, const ushort4* __restrict__ Kb,
    const int* __restrict__ rowstart, const int* __restrict__ csrcol,
    float* __restrict__ scores, int nnodes)
{
  const int n = blockIdx.x * 4 + (threadIdx.x >> 6);
  if (n >= nnodes) return;
  const int lane = threadIdx.x & 63;
  const int l5 = lane & 31;
  const int h  = lane >> 5;
  ushort4 qu = Qb[(unsigned)n * 32 + l5];
  const float4 q = make_float4(bf2f(qu.x), bf2f(qu.y), bf2f(qu.z), bf2f(qu.w));
  const int p0 = rowstart[n], p1 = rowstart[n+1];
  int p = p0;
  for (; p + 8 <= p1; p += 8){
    const int c0 = csrcol[p     + h], c1 = csrcol[p + 2 + h];
    const int c2 = csrcol[p + 4 + h], c3 = csrcol[p + 6 + h];
    ushort4 k0 = Kb[(unsigned)c0*32 + l5], k1 = Kb[(unsigned)c1*32 + l5];
    ushort4 k2 = Kb[(unsigned)c2*32 + l5], k3 = Kb[(unsigned)c3*32 + l5];
    float d0 = dotbf(q, k0), d1 = dotbf(q, k1), d2 = dotbf(q, k2), d3 = dotbf(q, k3);
    RED5(d0) RED5(d1) RED5(d2) RED5(d3)
    if (l5 == 0){
      scores[p     + h] = d0 * SC;
      scores[p + 2 + h] = d1 * SC;
      scores[p + 4 + h] = d2 * SC;
      scores[p + 6 + h] = d3 * SC;
    }
  }
  for (; p < p1; p += 2){
    const int idx = p + h;
    const bool valid = idx < p1;
    const int c = csrcol[valid ? idx : p];
    ushort4 ku = Kb[(unsigned)c*32 + l5];
    float d = dotbf(q, ku);
    RED5(d)
    if (valid && l5 == 0) scores[idx] = d * SC;
  }
}

// message1 (alpha-weighted Vb, ELU) fused with segment-mean of SM (fp32, strided)
__global__ __launch_bounds__(256) void k_passB(const ushort4* __restrict__ Vb, const float4* __restrict__ SM,
    int ldsm4, const float* __restrict__ sc, const float* __restrict__ Mp, const float* __restrict__ Ip,
    const int* __restrict__ rowstart, const int* __restrict__ csrcol,
    float4* __restrict__ Aout, float4* __restrict__ Bout, int ldb4, int nnodes)
{
  const int n = blockIdx.x * 4 + (threadIdx.x >> 6);
  if (n >= nnodes) return;
  const int lane = threadIdx.x & 63;
  const int l5 = lane & 31;
  const int h  = lane >> 5;
  const float M = Mp[0], inv = Ip[0];
  float4 av = make_float4(0.f, 0.f, 0.f, 0.f);
  float4 sv = make_float4(0.f, 0.f, 0.f, 0.f);
  const int p0 = rowstart[n], p1 = rowstart[n+1];
  int p = p0;
  for (; p + 8 <= p1; p += 8){
    const int c0 = csrcol[p     + h], c1 = csrcol[p + 2 + h];
    const int c2 = csrcol[p + 4 + h], c3 = csrcol[p + 6 + h];
    const float a0 = __expf(sc[p     + h] - M), a1 = __expf(sc[p + 2 + h] - M);
    const float a2 = __expf(sc[p + 4 + h] - M), a3 = __expf(sc[p + 6 + h] - M);
    ushort4 v0 = Vb[(unsigned)c0*32 + l5], v1 = Vb[(unsigned)c1*32 + l5];
    ushort4 v2 = Vb[(unsigned)c2*32 + l5], v3 = Vb[(unsigned)c3*32 + l5];
    float4 s0 = SM[(unsigned)c0*ldsm4 + l5], s1 = SM[(unsigned)c1*ldsm4 + l5];
    float4 s2 = SM[(unsigned)c2*ldsm4 + l5], s3 = SM[(unsigned)c3*ldsm4 + l5];
    av.x += a0*bf2f(v0.x) + a1*bf2f(v1.x) + a2*bf2f(v2.x) + a3*bf2f(v3.x);
    av.y += a0*bf2f(v0.y) + a1*bf2f(v1.y) + a2*bf2f(v2.y) + a3*bf2f(v3.y);
    av.z += a0*bf2f(v0.z) + a1*bf2f(v1.z) + a2*bf2f(v2.z) + a3*bf2f(v3.z);
    av.w += a0*bf2f(v0.w) + a1*bf2f(v1.w) + a2*bf2f(v2.w) + a3*bf2f(v3.w);
    sv.x += s0.x + s1.x + s2.x + s3.x;
    sv.y += s0.y + s1.y + s2.y + s3.y;
    sv.z += s0.z + s1.z + s2.z + s3.z;
    sv.w += s0.w + s1.w + s2.w + s3.w;
  }
  for (; p < p1; p += 2){
    const int idx = p + h;
    const bool valid = idx < p1;
    const int c = csrcol[valid ? idx : p];
    const float a = valid ? __expf(sc[idx] - M) : 0.f;
    ushort4 vu = Vb[(unsigned)c*32 + l5];
    float4 s = SM[(unsigned)c*ldsm4 + l5];
    av.x += a*bf2f(vu.x); av.y += a*bf2f(vu.y); av.z += a*bf2f(vu.z); av.w += a*bf2f(vu.w);
    if (valid){ sv.x += s.x; sv.y += s.y; sv.z += s.z; sv.w += s.w; }
  }
  av.x += __shfl_xor(av.x, 32, 64); av.y += __shfl_xor(av.y, 32, 64);
  av.z += __shfl_xor(av.z, 32, 64); av.w += __shfl_xor(av.w, 32, 64);
  sv.x += __shfl_xor(sv.x, 32, 64); sv.y += __shfl_xor(sv.y, 32, 64);
  sv.z += __shfl_xor(sv.z, 32, 64); sv.w += __shfl_xor(sv.w, 32, 64);
  if (h == 0){
    av.x *= inv; av.y *= inv; av.z *= inv; av.w *= inv;
    av.x = av.x > 0.f ? av.x : expm1f(av.x);
    av.y = av.y > 0.f ? av.y : expm1f(av.y);
    av.z = av.z > 0.f ? av.z : expm1f(av.z);
    av.w = av.w > 0.f ? av.w : expm1f(av.w);
    Aout[(unsigned)n * 32 + l5] = av;
    int dg = p1 - p0; if (dg < 1) dg = 1;
    const float invd = 1.f / (float)dg;
    Bout[(unsigned)n * ldb4 + l5] = make_float4(sv.x*invd, sv.y*invd, sv.z*invd, sv.w*invd);
  }
}

// message2 (alpha-weighted Vb, no activation) -> out
__global__ __launch_bounds__(256) void k_message2(const ushort4* __restrict__ Vb,
    const float* __restrict__ sc, const float* __restrict__ Mp, const float* __restrict__ Ip,
    const int* __restrict__ rowstart, const int* __restrict__ csrcol,
    float4* __restrict__ out4, int ldo4, int nnodes)
{
  const int n = blockIdx.x * 4 + (threadIdx.x >> 6);
  if (n >= nnodes) return;
  const int lane = threadIdx.x & 63;
  const int l5 = lane & 31;
  const int h  = lane >> 5;
  const float M = Mp[0], inv = Ip[0];
  float4 av = make_float4(0.f, 0.f, 0.f, 0.f);
  const int p0 = rowstart[n], p1 = rowstart[n+1];
  int p = p0;
  for (; p + 8 <= p1; p += 8){
    const int c0 = csrcol[p     + h], c1 = csrcol[p + 2 + h];
    const int c2 = csrcol[p + 4 + h], c3 = csrcol[p + 6 + h];
    const float a0 = __expf(sc[p     + h] - M), a1 = __expf(sc[p + 2 + h] - M);
    const float a2 = __expf(sc[p + 4 + h] - M), a3 = __expf(sc[p + 6 + h] - M);
    ushort4 v0 = Vb[(unsigned)c0*32 + l5], v1 = Vb[(unsigned)c1*32 + l5];
    ushort4 v2 = Vb[(unsigned)c2*32 + l5], v3 = Vb[(unsigned)c3*32 + l5];
    av.x += a0*bf2f(v0.x) + a1*bf2f(v1.x) + a2*bf2f(v2.x) + a3*bf2f(v3.x);
    av.y += a0*bf2f(v0.y) + a1*bf2f(v1.y) + a2*bf2f(v2.y) + a3*bf2f(v3.y);
    av.z += a0*bf2f(v0.z) + a1*bf2f(v1.z) + a2*bf2f(v2.z) + a3*bf2f(v3.z);
    av.w += a0*bf2f(v0.w) + a1*bf2f(v1.w) + a2*bf2f(v2.w) + a3*bf2f(v3.w);
  }
  for (; p < p1; p += 2){
    const int idx = p + h;
    const bool valid = idx < p1;
    const int c = csrcol[valid ? idx : p];
    const float a = valid ? __expf(sc[idx] - M) : 0.f;
    ushort4 vu = Vb[(unsigned)c*32 + l5];
    av.x += a*bf2f(vu.x); av.y += a*bf2f(vu.y); av.z += a*bf2f(vu.z); av.w += a*bf2f(vu.w);
  }
  av.x += __shfl_xor(av.x, 32, 64); av.y += __shfl_xor(av.y, 32, 64);
  av.z += __shfl_xor(av.z, 32, 64); av.w += __shfl_xor(av.w, 32, 64);
  if (h == 0)
    out4[(unsigned)n * ldo4 + l5] = make_float4(av.x*inv, av.y*inv, av.z*inv, av.w*inv);
}

// ---------------- fused online softmax reductions ----------------
__global__ __launch_bounds__(256) void k_sm_partial(const float* __restrict__ s, int n,
    float* __restrict__ pm, float* __restrict__ ps){
  __shared__ float sm_m[256], sm_s[256];
  const int tid = threadIdx.x;
  float m = -3.402823466e38f, sum = 0.f;
  for (int i = blockIdx.x * 256 + tid; i < n; i += gridDim.x * 256){
    float v = s[i];
    if (v <= m) sum += __expf(v - m);
    else { sum = sum * __expf(m - v) + 1.f; m = v; }
  }
  sm_m[tid] = m; sm_s[tid] = sum; __syncthreads();
  for (int off = 128; off > 0; off >>= 1){
    if (tid < off){
      float m2 = sm_m[tid + off], s2 = sm_s[tid + off];
      float m1 = sm_m[tid], s1 = sm_s[tid];
      float Mx = fmaxf(m1, m2);
      sm_m[tid] = Mx;
      sm_s[tid] = s1 * __expf(m1 - Mx) + s2 * __expf(m2 - Mx);
    }
    __syncthreads();
  }
  if (tid == 0){ pm[blockIdx.x] = sm_m[0]; ps[blockIdx.x] = sm_s[0]; }
}

__global__ __launch_bounds__(256) void k_sm_final(const float* __restrict__ pm, const float* __restrict__ ps,
    int n, float* __restrict__ Mout, float* __restrict__ Iout){
  __shared__ float sm_m[256], sm_s[256];
  const int tid = threadIdx.x;
  float m = -3.402823466e38f, sum = 0.f;
  for (int i = tid; i < n; i += 256){
    float m2 = pm[i], s2 = ps[i];
    float Mx = fmaxf(m, m2);
    sum = sum * __expf(m - Mx) + s2 * __expf(m2 - Mx);
    m = Mx;
  }
  sm_m[tid] = m; sm_s[tid] = sum; __syncthreads();
  for (int off = 128; off > 0; off >>= 1){
    if (tid < off){
      float m2 = sm_m[tid + off], s2 = sm_s[tid + off];
      float m1 = sm_m[tid], s1 = sm_s[tid];
      float Mx = fmaxf(m1, m2);
      sm_m[tid] = Mx;
      sm_s[tid] = s1 * __expf(m1 - Mx) + s2 * __expf(m2 - Mx);
    }
    __syncthreads();
  }
  if (tid == 0){ Mout[0] = sm_m[0]; Iout[0] = 1.f / sm_s[0]; }
}

extern "C" void kernel_launch(void* const* d_in, const int* in_sizes, int n_in,
                              void* d_out, int out_size, void* d_ws, size_t ws_size,
                              hipStream_t stream)
{
  const float* x   = (const float*)d_in[0];
  const int*   ei  = (const int*)d_in[1];
  const float* Wq1 = (const float*)d_in[2];  const float* bq1 = (const float*)d_in[3];
  const float* Wk1 = (const float*)d_in[4];  const float* bk1 = (const float*)d_in[5];
  const float* Wv1 = (const float*)d_in[6];  const float* bv1 = (const float*)d_in[7];
  const float* Wq2 = (const float*)d_in[8];  const float* bq2 = (const float*)d_in[9];
  const float* Wk2 = (const float*)d_in[10]; const float* bk2 = (const float*)d_in[11];
  const float* Wv2 = (const float*)d_in[12]; const float* bv2 = (const float*)d_in[13];
  const float* Ws1 = (const float*)d_in[14]; const float* bs1 = (const float*)d_in[15];
  const float* Ws2 = (const float*)d_in[16]; const float* bs2 = (const float*)d_in[17];

  const int N = in_sizes[0] / FD;
  const int E = in_sizes[1] / 2;
  const int* row = ei;
  const int* col = ei + E;
  float* out = (float*)d_out;

  char* ws = (char*)d_ws;
  size_t off = 0;
  auto alloc = [&](size_t bytes) -> void* {
    void* p = ws + off;
    off += (bytes + 255) & ~(size_t)255;
    return p;
  };
  int* deg      = (int*)alloc((size_t)N * 4);
  int* rowstart = (int*)alloc((size_t)(N + 1) * 4);
  int* cursor   = (int*)alloc((size_t)N * 4);
  int* csrcol   = (int*)alloc((size_t)E * 4);
  float* scores = (float*)alloc((size_t)E * 4);
  float* pm     = (float*)alloc(1024);
  float* ps     = (float*)alloc(1024);
  float* Mv     = (float*)alloc(256);
  float* Iv     = (float*)alloc(256);
  unsigned short* Qb = (unsigned short*)alloc((size_t)N * FD * 2);
  unsigned short* Kb = (unsigned short*)alloc((size_t)N * FD * 2);
  unsigned short* Vb = (unsigned short*)alloc((size_t)N * FD * 2);
  float* A = (float*)alloc((size_t)N * FD * 4);   // h (fp32, gemm input)
  (void)ws_size; (void)n_in; (void)out_size;

  hipMemsetAsync(deg, 0, (size_t)N * 4, stream);
  hipMemsetAsync(cursor, 0, (size_t)N * 4, stream);

  const int eb = 2048;
  k_count_deg<<<eb, 256, 0, stream>>>(row, E, deg);
  k_scan_excl<<<1, 1024, 0, stream>>>(deg, rowstart, N);
  k_fill_csr<<<eb, 256, 0, stream>>>(row, col, E, rowstart, cursor, csrcol);

  const int gb = (N + 63) / 64;
  const int nb = (N + 3) / 4;
  const int rb = 256;

  // SM = seg-mean scratch in out cols [0,128); B = seg scratch in out cols [128,256). ld = 256 floats.
  float* SM = out;
  float* B  = out + FD;

  // ---- layer-1 QKV (bf16 outputs) ----
  k_gemm<0,1><<<gb, 256, 0, stream>>>(x, FD, Wq1, bq1, Qb, FD, N);
  k_gemm<0,1><<<gb, 256, 0, stream>>>(x, FD, Wk1, bk1, Kb, FD, N);
  k_gemm<0,1><<<gb, 256, 0, stream>>>(x, FD, Wv1, bv1, Vb, FD, N);

  // ---- fused: scores1 + seg_mean(x) -> SM ----
  k_passA<<<nb, 256, 0, stream>>>((const ushort4*)Qb, (const ushort4*)Kb, (const float4*)x,
                                  rowstart, csrcol, scores, (float4*)SM, 64, N);

  k_sm_partial<<<rb, 256, 0, stream>>>(scores, E, pm, ps);
  k_sm_final<<<1, 256, 0, stream>>>(pm, ps, rb, Mv, Iv);

  // s1 = relu(SM @ Ws1^T + bs1), in place (ld 256)
  k_gemm<1,0><<<gb, 256, 0, stream>>>(SM, 2*FD, Ws1, bs1, SM, 2*FD, N);

  // ---- fused: message1(Vb)+ELU -> A; seg_mean(s1=SM) -> B ----
  k_passB<<<nb, 256, 0, stream>>>((const ushort4*)Vb, (const float4*)SM, 64, scores, Mv, Iv,
                                  rowstart, csrcol, (float4*)A, (float4*)B, 64, N);

  // ss_out = relu(B @ Ws2^T + bs2) -> out cols [128,256), in place
  k_gemm<1,0><<<gb, 256, 0, stream>>>(B, 2*FD, Ws2, bs2, B, 2*FD, N);

  // ---- layer-2 QK (bf16) ----
  k_gemm<0,1><<<gb, 256, 0, stream>>>(A, FD, Wq2, bq2, Qb, FD, N);
  k_gemm<0,1><<<gb, 256, 0, stream>>>(A, FD, Wk2, bk2, Kb, FD, N);
  k_scores2<<<nb, 256, 0, stream>>>((const ushort4*)Qb, (const ushort4*)Kb, rowstart, csrcol, scores, N);

  k_sm_partial<<<rb, 256, 0, stream>>>(scores, E, pm, ps);
  k_sm_final<<<1, 256, 0, stream>>>(pm, ps, rb, Mv, Iv);

  // V2 (bf16) then message2 -> out cols [0,128)
  k_gemm<0,1><<<gb, 256, 0, stream>>>(A, FD, Wv2, bv2, Vb, FD, N);
  k_message2<<<nb, 256, 0, stream>>>((const ushort4*)Vb, scores, Mv, Iv, rowstart, csrcol,
                                     (float4*)out, 64, N);
}

// Round 4
// 554.447 us; speedup vs baseline: 2.3417x; 1.3311x over previous
//
#include <hip/hip_runtime.h>
#include <math.h>

#define FD 128

typedef __attribute__((ext_vector_type(8))) short short8v;
typedef __attribute__((ext_vector_type(4))) float float4v;

static __device__ __forceinline__ float bf2f(unsigned short u){
  return __uint_as_float(((unsigned int)u) << 16);
}
static __device__ __forceinline__ unsigned short f2bf(float f){
  unsigned int x = __float_as_uint(f);
  x += 0x7fff + ((x >> 16) & 1);   // RNE
  return (unsigned short)(x >> 16);
}

// ---------------- conversions ----------------
__global__ void k_cvt_x(const float4* __restrict__ in, ushort4* __restrict__ out, int n4){
  int i = blockIdx.x * 256 + threadIdx.x, st = gridDim.x * 256;
  for (; i < n4; i += st){
    float4 v = in[i];
    out[i] = make_ushort4(f2bf(v.x), f2bf(v.y), f2bf(v.z), f2bf(v.w));
  }
}

__global__ __launch_bounds__(256) void k_cvt_w(const float* __restrict__ w0, const float* __restrict__ w1,
    const float* __restrict__ w2, const float* __restrict__ w3, const float* __restrict__ w4,
    const float* __restrict__ w5, unsigned short* __restrict__ dst){
  int i = blockIdx.x * 256 + threadIdx.x;
  if (i >= FD * FD) return;
  dst[i]           = f2bf(w0[i]);
  dst[FD*FD   + i] = f2bf(w1[i]);
  dst[2*FD*FD + i] = f2bf(w2[i]);
  dst[3*FD*FD + i] = f2bf(w3[i]);
  dst[4*FD*FD + i] = f2bf(w4[i]);
  dst[5*FD*FD + i] = f2bf(w5[i]);
}

// ---------------- CSR build ----------------
__global__ void k_count_deg(const int* __restrict__ row, int E, int* __restrict__ deg){
  int i = blockIdx.x * blockDim.x + threadIdx.x;
  int stride = gridDim.x * blockDim.x;
  for (; i < E; i += stride) atomicAdd(&deg[row[i]], 1);
}

// block scans 1024 elems (4/thread); writes per-elem exclusive (within block) + block total
__global__ __launch_bounds__(256) void k_scan_blk(const int* __restrict__ in, int n,
    int* __restrict__ out, int* __restrict__ blksum){
  __shared__ int sm[256];
  const int tid = threadIdx.x;
  const int base = blockIdx.x * 1024;
  const int idx = base + tid * 4;
  int v0=0,v1=0,v2=0,v3=0;
  if (idx + 3 < n){ int4 t = *(const int4*)(in + idx); v0=t.x; v1=t.y; v2=t.z; v3=t.w; }
  else {
    if (idx   < n) v0 = in[idx];
    if (idx+1 < n) v1 = in[idx+1];
    if (idx+2 < n) v2 = in[idx+2];
    if (idx+3 < n) v3 = in[idx+3];
  }
  int s = v0+v1+v2+v3;
  sm[tid] = s; __syncthreads();
  for (int off = 1; off < 256; off <<= 1){
    int t = (tid >= off) ? sm[tid-off] : 0;
    __syncthreads();
    sm[tid] += t;
    __syncthreads();
  }
  int excl = sm[tid] - s;
  if (tid == 255) blksum[blockIdx.x] = sm[255];
  if (idx   < n) out[idx]   = excl;
  if (idx+1 < n) out[idx+1] = excl + v0;
  if (idx+2 < n) out[idx+2] = excl + v0 + v1;
  if (idx+3 < n) out[idx+3] = excl + v0 + v1 + v2;
}

__global__ __launch_bounds__(256) void k_scan_part(const int* __restrict__ blksum, int nblk,
    int* __restrict__ blkoff){
  __shared__ int sm[256];
  const int tid = threadIdx.x;
  int v = (tid < nblk) ? blksum[tid] : 0;
  sm[tid] = v; __syncthreads();
  for (int off = 1; off < 256; off <<= 1){
    int t = (tid >= off) ? sm[tid-off] : 0;
    __syncthreads();
    sm[tid] += t;
    __syncthreads();
  }
  if (tid < nblk) blkoff[tid] = sm[tid] - v;
}

__global__ __launch_bounds__(256) void k_scan_add(int* __restrict__ out, int n,
    const int* __restrict__ blkoff, int E){
  int i = blockIdx.x * 256 + threadIdx.x;
  if (i < n) out[i] += blkoff[i >> 10];
  if (i == 0) out[n] = E;
}

__global__ void k_fill_csr(const int* __restrict__ row, const int* __restrict__ col, int E,
                           const int* __restrict__ rowstart, int* __restrict__ cursor,
                           int* __restrict__ csrcol){
  int i = blockIdx.x * blockDim.x + threadIdx.x;
  int stride = gridDim.x * blockDim.x;
  for (; i < E; i += stride){
    int r = row[i];
    int pos = rowstart[r] + atomicAdd(&cursor[r], 1);
    csrcol[pos] = col[i];
  }
}

// ---------------- MFMA GEMM: Y_bf16 = Xb @ Wb^T + bias; per wave 16 rows x 128 cols ----
__global__ __launch_bounds__(256) void k_gemm_mfma(const unsigned short* __restrict__ X,
    const unsigned short* __restrict__ W, const float* __restrict__ bias,
    unsigned short* __restrict__ Y, int nrows)
{
  const int wid  = threadIdx.x >> 6;
  const int lane = threadIdx.x & 63;
  const int r0 = blockIdx.x * 64 + wid * 16;
  if (r0 >= nrows) return;
  const int l4 = lane & 15;
  const int kg = lane >> 4;                 // 0..3
  int rA = r0 + l4; if (rA > nrows - 1) rA = nrows - 1;
  short8v a[4];
  #pragma unroll
  for (int ks = 0; ks < 4; ks++)
    a[ks] = *(const short8v*)(X + (size_t)rA * FD + ks*32 + kg*8);
  float4v acc[8];
  #pragma unroll
  for (int t = 0; t < 8; t++)
    #pragma unroll
    for (int i = 0; i < 4; i++) acc[t][i] = 0.f;
  #pragma unroll
  for (int t = 0; t < 8; t++){
    const int cB = t*16 + l4;
    #pragma unroll
    for (int ks = 0; ks < 4; ks++){
      short8v b = *(const short8v*)(W + (size_t)cB * FD + ks*32 + kg*8);
      acc[t] = __builtin_amdgcn_mfma_f32_16x16x32_bf16(a[ks], b, acc[t], 0, 0, 0);
    }
  }
  #pragma unroll
  for (int t = 0; t < 8; t++){
    const int c = t*16 + l4;
    const float bc = bias[c];
    #pragma unroll
    for (int i = 0; i < 4; i++){
      const int r = r0 + kg*4 + i;    // C/D: col=lane&15, row=(lane>>4)*4+reg  [m89]
      if (r < nrows) Y[(size_t)r * FD + c] = f2bf(acc[t][i] + bc);
    }
  }
}

// ---------------- fp32 VALU GEMM (ss path): Y = relu(X @ W^T + b) ----------------
template<int ACT, int OUTBF>
__global__ __launch_bounds__(256) void k_gemm(const float* __restrict__ X, int ldx,
    const float* __restrict__ W, const float* __restrict__ bias,
    void* __restrict__ Y, int ldy, int nrows)
{
  __shared__ float sX[64][68];
  __shared__ float sW[128][68];
  const int tid = threadIdx.x;
  const int row0 = blockIdx.x * 64;
  const int tr = tid >> 5;
  const int tc = tid & 31;
  float acc[8][4];
  #pragma unroll
  for (int i = 0; i < 8; i++)
    #pragma unroll
    for (int j = 0; j < 4; j++) acc[i][j] = 0.f;

  for (int kk = 0; kk < FD; kk += 64){
    for (int i = tid; i < 64 * 16; i += 256){
      int r = i >> 4, c4 = (i & 15) << 2;
      float4 v = make_float4(0.f, 0.f, 0.f, 0.f);
      if (row0 + r < nrows) v = *(const float4*)(X + (size_t)(row0 + r) * ldx + kk + c4);
      *(float4*)&sX[r][c4] = v;
    }
    for (int i = tid; i < 128 * 16; i += 256){
      int r = i >> 4, c4 = (i & 15) << 2;
      *(float4*)&sW[r][c4] = *(const float4*)(W + (size_t)r * FD + kk + c4);
    }
    __syncthreads();
    #pragma unroll 4
    for (int d = 0; d < 64; d += 4){
      float4 xv[8], wv[4];
      #pragma unroll
      for (int i = 0; i < 8; i++) xv[i] = *(const float4*)&sX[8*tr + i][d];
      #pragma unroll
      for (int j = 0; j < 4; j++) wv[j] = *(const float4*)&sW[tc + 32*j][d];
      #pragma unroll
      for (int i = 0; i < 8; i++)
        #pragma unroll
        for (int j = 0; j < 4; j++)
          acc[i][j] += xv[i].x*wv[j].x + xv[i].y*wv[j].y + xv[i].z*wv[j].z + xv[i].w*wv[j].w;
    }
    __syncthreads();
  }
  float bj[4];
  #pragma unroll
  for (int j = 0; j < 4; j++) bj[j] = bias[tc + 32*j];
  #pragma unroll
  for (int i = 0; i < 8; i++){
    int r = row0 + 8*tr + i;
    if (r < nrows){
      #pragma unroll
      for (int j = 0; j < 4; j++){
        float v = acc[i][j] + bj[j];
        if (ACT == 1) v = fmaxf(v, 0.f);
        if (OUTBF) ((unsigned short*)Y)[(size_t)r * ldy + tc + 32*j] = f2bf(v);
        else       ((float*)Y)[(size_t)r * ldy + tc + 32*j] = v;
      }
    }
  }
}

// ---------------- edge passes: 1 wave = 1 node, 32 lanes/row, 8 edges per half-wave ----
#define RED5(d) \
  d += __shfl_xor(d, 16, 64); d += __shfl_xor(d, 8, 64); \
  d += __shfl_xor(d,  4, 64); d += __shfl_xor(d, 2, 64); d += __shfl_xor(d, 1, 64);

#define SC 0.08838834764831845f

static __device__ __forceinline__ float dotbf(float4 q, ushort4 k){
  return q.x*bf2f(k.x) + q.y*bf2f(k.y) + q.z*bf2f(k.z) + q.w*bf2f(k.w);
}

// scores1 (Qb.Kb) fused with segment-mean of X (fp32 gather, precision-critical)
__global__ __launch_bounds__(256) void k_passA(const ushort4* __restrict__ Qb, const ushort4* __restrict__ Kb,
    const float4* __restrict__ X, const int* __restrict__ rowstart, const int* __restrict__ csrcol,
    float* __restrict__ scores, float4* __restrict__ segout, int ldseg4, int nnodes)
{
  const int n = blockIdx.x * 4 + (threadIdx.x >> 6);
  if (n >= nnodes) return;
  const int lane = threadIdx.x & 63, l5 = lane & 31, h = lane >> 5;
  ushort4 qu = Qb[(unsigned)n * 32 + l5];
  const float4 q = make_float4(bf2f(qu.x), bf2f(qu.y), bf2f(qu.z), bf2f(qu.w));
  float4 sx = make_float4(0.f, 0.f, 0.f, 0.f);
  const int p0 = rowstart[n], p1 = rowstart[n+1];
  const int last = p1 - 1;
  for (int p = p0; p < p1; p += 16){
    int idx[8], cc[8];
    #pragma unroll
    for (int k = 0; k < 8; k++){
      idx[k] = p + 2*k + h;
      cc[k] = csrcol[idx[k] < p1 ? idx[k] : last];
    }
    ushort4 kv[8]; float4 xv[8];
    #pragma unroll
    for (int k = 0; k < 8; k++){
      kv[k] = Kb[(unsigned)cc[k]*32 + l5];
      xv[k] = X [(unsigned)cc[k]*32 + l5];
    }
    float d[8];
    #pragma unroll
    for (int k = 0; k < 8; k++){
      d[k] = dotbf(q, kv[k]);
      const float m = idx[k] < p1 ? 1.f : 0.f;
      sx.x += m*xv[k].x; sx.y += m*xv[k].y; sx.z += m*xv[k].z; sx.w += m*xv[k].w;
    }
    #pragma unroll
    for (int k = 0; k < 8; k++){ RED5(d[k]) }
    if (l5 == 0){
      #pragma unroll
      for (int k = 0; k < 8; k++)
        if (idx[k] < p1) scores[idx[k]] = d[k] * SC;
    }
  }
  sx.x += __shfl_xor(sx.x, 32, 64); sx.y += __shfl_xor(sx.y, 32, 64);
  sx.z += __shfl_xor(sx.z, 32, 64); sx.w += __shfl_xor(sx.w, 32, 64);
  int dg = p1 - p0; if (dg < 1) dg = 1;
  const float inv = 1.f / (float)dg;
  if (h == 0)
    segout[(unsigned)n * ldseg4 + l5] = make_float4(sx.x*inv, sx.y*inv, sx.z*inv, sx.w*inv);
}

// scores (layer 2)
__global__ __launch_bounds__(256) void k_scores2(const ushort4* __restrict__ Qb, const ushort4* __restrict__ Kb,
    const int* __restrict__ rowstart, const int* __restrict__ csrcol,
    float* __restrict__ scores, int nnodes)
{
  const int n = blockIdx.x * 4 + (threadIdx.x >> 6);
  if (n >= nnodes) return;
  const int lane = threadIdx.x & 63, l5 = lane & 31, h = lane >> 5;
  const int p0 = rowstart[n], p1 = rowstart[n+1];
  if (p0 >= p1) return;
  ushort4 qu = Qb[(unsigned)n * 32 + l5];
  const float4 q = make_float4(bf2f(qu.x), bf2f(qu.y), bf2f(qu.z), bf2f(qu.w));
  const int last = p1 - 1;
  for (int p = p0; p < p1; p += 16){
    int idx[8], cc[8];
    #pragma unroll
    for (int k = 0; k < 8; k++){
      idx[k] = p + 2*k + h;
      cc[k] = csrcol[idx[k] < p1 ? idx[k] : last];
    }
    ushort4 kv[8];
    #pragma unroll
    for (int k = 0; k < 8; k++) kv[k] = Kb[(unsigned)cc[k]*32 + l5];
    float d[8];
    #pragma unroll
    for (int k = 0; k < 8; k++) d[k] = dotbf(q, kv[k]);
    #pragma unroll
    for (int k = 0; k < 8; k++){ RED5(d[k]) }
    if (l5 == 0){
      #pragma unroll
      for (int k = 0; k < 8; k++)
        if (idx[k] < p1) scores[idx[k]] = d[k] * SC;
    }
  }
}

// message1 (alpha-weighted Vb, ELU -> Ab bf16) fused with segment-mean of Sb (bf16)
__global__ __launch_bounds__(256) void k_passB(const ushort4* __restrict__ Vb, const ushort4* __restrict__ Sb,
    const float* __restrict__ sc, const float* __restrict__ Mp, const float* __restrict__ Ip,
    const int* __restrict__ rowstart, const int* __restrict__ csrcol,
    ushort4* __restrict__ Ab, float4* __restrict__ Bout, int ldb4, int nnodes)
{
  const int n = blockIdx.x * 4 + (threadIdx.x >> 6);
  if (n >= nnodes) return;
  const int lane = threadIdx.x & 63, l5 = lane & 31, h = lane >> 5;
  const float M = Mp[0], inv = Ip[0];
  float4 av = make_float4(0.f, 0.f, 0.f, 0.f);
  float4 sv = make_float4(0.f, 0.f, 0.f, 0.f);
  const int p0 = rowstart[n], p1 = rowstart[n+1];
  const int last = p1 - 1;
  for (int p = p0; p < p1; p += 16){
    int idx[8], cc[8]; float aa[8];
    #pragma unroll
    for (int k = 0; k < 8; k++){
      idx[k] = p + 2*k + h;
      const int eff = idx[k] < p1 ? idx[k] : last;
      cc[k] = csrcol[eff];
      aa[k] = sc[eff];
    }
    ushort4 vv[8], ss[8];
    #pragma unroll
    for (int k = 0; k < 8; k++){
      vv[k] = Vb[(unsigned)cc[k]*32 + l5];
      ss[k] = Sb[(unsigned)cc[k]*32 + l5];
    }
    #pragma unroll
    for (int k = 0; k < 8; k++){
      const float m = idx[k] < p1 ? 1.f : 0.f;
      const float a = m * __expf(aa[k] - M);
      av.x += a*bf2f(vv[k].x); av.y += a*bf2f(vv[k].y);
      av.z += a*bf2f(vv[k].z); av.w += a*bf2f(vv[k].w);
      sv.x += m*bf2f(ss[k].x); sv.y += m*bf2f(ss[k].y);
      sv.z += m*bf2f(ss[k].z); sv.w += m*bf2f(ss[k].w);
    }
  }
  av.x += __shfl_xor(av.x, 32, 64); av.y += __shfl_xor(av.y, 32, 64);
  av.z += __shfl_xor(av.z, 32, 64); av.w += __shfl_xor(av.w, 32, 64);
  sv.x += __shfl_xor(sv.x, 32, 64); sv.y += __shfl_xor(sv.y, 32, 64);
  sv.z += __shfl_xor(sv.z, 32, 64); sv.w += __shfl_xor(sv.w, 32, 64);
  if (h == 0){
    av.x *= inv; av.y *= inv; av.z *= inv; av.w *= inv;
    av.x = av.x > 0.f ? av.x : expm1f(av.x);
    av.y = av.y > 0.f ? av.y : expm1f(av.y);
    av.z = av.z > 0.f ? av.z : expm1f(av.z);
    av.w = av.w > 0.f ? av.w : expm1f(av.w);
    Ab[(unsigned)n * 32 + l5] = make_ushort4(f2bf(av.x), f2bf(av.y), f2bf(av.z), f2bf(av.w));
    int dg = p1 - p0; if (dg < 1) dg = 1;
    const float invd = 1.f / (float)dg;
    Bout[(unsigned)n * ldb4 + l5] = make_float4(sv.x*invd, sv.y*invd, sv.z*invd, sv.w*invd);
  }
}

// message2 -> out
__global__ __launch_bounds__(256) void k_message2(const ushort4* __restrict__ Vb,
    const float* __restrict__ sc, const float* __restrict__ Mp, const float* __restrict__ Ip,
    const int* __restrict__ rowstart, const int* __restrict__ csrcol,
    float4* __restrict__ out4, int ldo4, int nnodes)
{
  const int n = blockIdx.x * 4 + (threadIdx.x >> 6);
  if (n >= nnodes) return;
  const int lane = threadIdx.x & 63, l5 = lane & 31, h = lane >> 5;
  const float M = Mp[0], inv = Ip[0];
  float4 av = make_float4(0.f, 0.f, 0.f, 0.f);
  const int p0 = rowstart[n], p1 = rowstart[n+1];
  const int last = p1 - 1;
  for (int p = p0; p < p1; p += 16){
    int idx[8], cc[8]; float aa[8];
    #pragma unroll
    for (int k = 0; k < 8; k++){
      idx[k] = p + 2*k + h;
      const int eff = idx[k] < p1 ? idx[k] : last;
      cc[k] = csrcol[eff];
      aa[k] = sc[eff];
    }
    ushort4 vv[8];
    #pragma unroll
    for (int k = 0; k < 8; k++) vv[k] = Vb[(unsigned)cc[k]*32 + l5];
    #pragma unroll
    for (int k = 0; k < 8; k++){
      const float m = idx[k] < p1 ? 1.f : 0.f;
      const float a = m * __expf(aa[k] - M);
      av.x += a*bf2f(vv[k].x); av.y += a*bf2f(vv[k].y);
      av.z += a*bf2f(vv[k].z); av.w += a*bf2f(vv[k].w);
    }
  }
  av.x += __shfl_xor(av.x, 32, 64); av.y += __shfl_xor(av.y, 32, 64);
  av.z += __shfl_xor(av.z, 32, 64); av.w += __shfl_xor(av.w, 32, 64);
  if (h == 0)
    out4[(unsigned)n * ldo4 + l5] = make_float4(av.x*inv, av.y*inv, av.z*inv, av.w*inv);
}

// ---------------- fused online softmax reductions ----------------
__global__ __launch_bounds__(256) void k_sm_partial(const float* __restrict__ s, int n,
    float* __restrict__ pm, float* __restrict__ ps){
  __shared__ float sm_m[256], sm_s[256];
  const int tid = threadIdx.x;
  float m = -3.402823466e38f, sum = 0.f;
  for (int i = blockIdx.x * 256 + tid; i < n; i += gridDim.x * 256){
    float v = s[i];
    if (v <= m) sum += __expf(v - m);
    else { sum = sum * __expf(m - v) + 1.f; m = v; }
  }
  sm_m[tid] = m; sm_s[tid] = sum; __syncthreads();
  for (int off = 128; off > 0; off >>= 1){
    if (tid < off){
      float m2 = sm_m[tid + off], s2 = sm_s[tid + off];
      float m1 = sm_m[tid], s1 = sm_s[tid];
      float Mx = fmaxf(m1, m2);
      sm_m[tid] = Mx;
      sm_s[tid] = s1 * __expf(m1 - Mx) + s2 * __expf(m2 - Mx);
    }
    __syncthreads();
  }
  if (tid == 0){ pm[blockIdx.x] = sm_m[0]; ps[blockIdx.x] = sm_s[0]; }
}

__global__ __launch_bounds__(256) void k_sm_final(const float* __restrict__ pm, const float* __restrict__ ps,
    int n, float* __restrict__ Mout, float* __restrict__ Iout){
  __shared__ float sm_m[256], sm_s[256];
  const int tid = threadIdx.x;
  float m = -3.402823466e38f, sum = 0.f;
  for (int i = tid; i < n; i += 256){
    float m2 = pm[i], s2 = ps[i];
    float Mx = fmaxf(m, m2);
    sum = sum * __expf(m - Mx) + s2 * __expf(m2 - Mx);
    m = Mx;
  }
  sm_m[tid] = m; sm_s[tid] = sum; __syncthreads();
  for (int off = 128; off > 0; off >>= 1){
    if (tid < off){
      float m2 = sm_m[tid + off], s2 = sm_s[tid + off];
      float m1 = sm_m[tid], s1 = sm_s[tid];
      float Mx = fmaxf(m1, m2);
      sm_m[tid] = Mx;
      sm_s[tid] = s1 * __expf(m1 - Mx) + s2 * __expf(m2 - Mx);
    }
    __syncthreads();
  }
  if (tid == 0){ Mout[0] = sm_m[0]; Iout[0] = 1.f / sm_s[0]; }
}

extern "C" void kernel_launch(void* const* d_in, const int* in_sizes, int n_in,
                              void* d_out, int out_size, void* d_ws, size_t ws_size,
                              hipStream_t stream)
{
  const float* x   = (const float*)d_in[0];
  const int*   ei  = (const int*)d_in[1];
  const float* Wq1 = (const float*)d_in[2];  const float* bq1 = (const float*)d_in[3];
  const float* Wk1 = (const float*)d_in[4];  const float* bk1 = (const float*)d_in[5];
  const float* Wv1 = (const float*)d_in[6];  const float* bv1 = (const float*)d_in[7];
  const float* Wq2 = (const float*)d_in[8];  const float* bq2 = (const float*)d_in[9];
  const float* Wk2 = (const float*)d_in[10]; const float* bk2 = (const float*)d_in[11];
  const float* Wv2 = (const float*)d_in[12]; const float* bv2 = (const float*)d_in[13];
  const float* Ws1 = (const float*)d_in[14]; const float* bs1 = (const float*)d_in[15];
  const float* Ws2 = (const float*)d_in[16]; const float* bs2 = (const float*)d_in[17];

  const int N = in_sizes[0] / FD;
  const int E = in_sizes[1] / 2;
  const int* row = ei;
  const int* col = ei + E;
  float* out = (float*)d_out;

  char* ws = (char*)d_ws;
  size_t off = 0;
  auto alloc = [&](size_t bytes) -> void* {
    void* p = ws + off;
    off += (bytes + 255) & ~(size_t)255;
    return p;
  };
  int* deg      = (int*)alloc((size_t)N * 4);
  int* rowstart = (int*)alloc((size_t)(N + 1) * 4);
  int* cursor   = (int*)alloc((size_t)N * 4);
  int* csrcol   = (int*)alloc((size_t)E * 4);
  float* scores = (float*)alloc((size_t)E * 4);
  int* blksum   = (int*)alloc(1024);
  int* blkoff   = (int*)alloc(1024);
  float* pm     = (float*)alloc(1024);
  float* ps     = (float*)alloc(1024);
  float* Mv     = (float*)alloc(256);
  float* Iv     = (float*)alloc(256);
  unsigned short* Qb = (unsigned short*)alloc((size_t)N * FD * 2);
  unsigned short* Kb = (unsigned short*)alloc((size_t)N * FD * 2);
  unsigned short* Vb = (unsigned short*)alloc((size_t)N * FD * 2);
  unsigned short* Xb = (unsigned short*)alloc((size_t)N * FD * 2);  // aliased as Sb after QKV1
  unsigned short* Ab = (unsigned short*)alloc((size_t)N * FD * 2);
  unsigned short* Wb = (unsigned short*)alloc((size_t)6 * FD * FD * 2);
  unsigned short* Sb = Xb;   // s1 (bf16); Xb is dead once QKV1 GEMMs complete
  (void)ws_size; (void)n_in; (void)out_size;

  hipMemsetAsync(deg, 0, (size_t)N * 4, stream);
  hipMemsetAsync(cursor, 0, (size_t)N * 4, stream);

  // conversions
  k_cvt_x<<<2048, 256, 0, stream>>>((const float4*)x, (ushort4*)Xb, N * FD / 4);
  k_cvt_w<<<(FD*FD + 255)/256, 256, 0, stream>>>(Wq1, Wk1, Wv1, Wq2, Wk2, Wv2, Wb);

  // CSR
  const int eb = 2048;
  const int nblk = (N + 1023) / 1024;
  k_count_deg<<<eb, 256, 0, stream>>>(row, E, deg);
  k_scan_blk<<<nblk, 256, 0, stream>>>(deg, N, rowstart, blksum);
  k_scan_part<<<1, 256, 0, stream>>>(blksum, nblk, blkoff);
  k_scan_add<<<(N + 255)/256, 256, 0, stream>>>(rowstart, N, blkoff, E);
  k_fill_csr<<<eb, 256, 0, stream>>>(row, col, E, rowstart, cursor, csrcol);

  const int gb  = (N + 63) / 64;   // both gemm grids (64 rows/block)
  const int nb  = (N + 3) / 4;
  const int rb  = 256;

  float* SM = out;           // seg_mean(x) scratch: out cols [0,128), ld 256
  float* B  = out + FD;      // seg_mean(s1) scratch: out cols [128,256), ld 256

  // ---- layer-1 QKV (MFMA bf16) ----
  k_gemm_mfma<<<gb, 256, 0, stream>>>(Xb, Wb + 0*FD*FD, bq1, Qb, N);
  k_gemm_mfma<<<gb, 256, 0, stream>>>(Xb, Wb + 1*FD*FD, bk1, Kb, N);
  k_gemm_mfma<<<gb, 256, 0, stream>>>(Xb, Wb + 2*FD*FD, bv1, Vb, N);

  // ---- fused: scores1 + seg_mean(x fp32) -> SM ----
  k_passA<<<nb, 256, 0, stream>>>((const ushort4*)Qb, (const ushort4*)Kb, (const float4*)x,
                                  rowstart, csrcol, scores, (float4*)SM, 64, N);

  k_sm_partial<<<rb, 256, 0, stream>>>(scores, E, pm, ps);
  k_sm_final<<<1, 256, 0, stream>>>(pm, ps, rb, Mv, Iv);

  // s1 = relu(SM @ Ws1^T + bs1) -> Sb (bf16)   [Xb dead: QKV1 done]
  k_gemm<1,1><<<gb, 256, 0, stream>>>(SM, 2*FD, Ws1, bs1, Sb, FD, N);

  // ---- fused: message1+ELU -> Ab (bf16 h); seg_mean(s1) -> B ----
  k_passB<<<nb, 256, 0, stream>>>((const ushort4*)Vb, (const ushort4*)Sb, scores, Mv, Iv,
                                  rowstart, csrcol, (ushort4*)Ab, (float4*)B, 64, N);

  // ss_out = relu(B @ Ws2^T + bs2), in place (out cols [128,256))
  k_gemm<1,0><<<gb, 256, 0, stream>>>(B, 2*FD, Ws2, bs2, B, 2*FD, N);

  // ---- layer-2 QK (MFMA bf16) ----
  k_gemm_mfma<<<gb, 256, 0, stream>>>(Ab, Wb + 3*FD*FD, bq2, Qb, N);
  k_gemm_mfma<<<gb, 256, 0, stream>>>(Ab, Wb + 4*FD*FD, bk2, Kb, N);
  k_scores2<<<nb, 256, 0, stream>>>((const ushort4*)Qb, (const ushort4*)Kb, rowstart, csrcol, scores, N);

  k_sm_partial<<<rb, 256, 0, stream>>>(scores, E, pm, ps);
  k_sm_final<<<1, 256, 0, stream>>>(pm, ps, rb, Mv, Iv);

  // V2 (MFMA) then message2 -> out cols [0,128)
  k_gemm_mfma<<<gb, 256, 0, stream>>>(Ab, Wb + 5*FD*FD, bv2, Vb, N);
  k_message2<<<nb, 256, 0, stream>>>((const ushort4*)Vb, scores, Mv, Iv, rowstart, csrcol,
                                     (float4*)out, 64, N);
}

// Round 5
// 486.526 us; speedup vs baseline: 2.6686x; 1.1396x over previous
//
#include <hip/hip_runtime.h>
#include <math.h>

#define FD 128

typedef __attribute__((ext_vector_type(8))) _Float16 half8v;
typedef __attribute__((ext_vector_type(4))) _Float16 half4v;
typedef __attribute__((ext_vector_type(4))) float float4v;

// ---------------- conversions ----------------
__global__ void k_cvt_x(const float4* __restrict__ in, half4v* __restrict__ out, int n4){
  int i = blockIdx.x * 256 + threadIdx.x, st = gridDim.x * 256;
  for (; i < n4; i += st){
    float4 v = in[i];
    half4v o;
    o[0] = (_Float16)v.x; o[1] = (_Float16)v.y; o[2] = (_Float16)v.z; o[3] = (_Float16)v.w;
    out[i] = o;
  }
}

__global__ __launch_bounds__(256) void k_cvt_w(
    const float* __restrict__ w0, const float* __restrict__ w1, const float* __restrict__ w2,
    const float* __restrict__ w3, const float* __restrict__ w4, const float* __restrict__ w5,
    const float* __restrict__ w6, const float* __restrict__ w7, _Float16* __restrict__ dst){
  int i = blockIdx.x * 256 + threadIdx.x;
  if (i >= FD * FD) return;
  dst[0*FD*FD + i] = (_Float16)w0[i];
  dst[1*FD*FD + i] = (_Float16)w1[i];
  dst[2*FD*FD + i] = (_Float16)w2[i];
  dst[3*FD*FD + i] = (_Float16)w3[i];
  dst[4*FD*FD + i] = (_Float16)w4[i];
  dst[5*FD*FD + i] = (_Float16)w5[i];
  dst[6*FD*FD + i] = (_Float16)w6[i];
  dst[7*FD*FD + i] = (_Float16)w7[i];
}

// ---------------- CSR build ----------------
__global__ void k_count_deg(const int* __restrict__ row, int E, int* __restrict__ deg){
  int i = blockIdx.x * blockDim.x + threadIdx.x;
  int stride = gridDim.x * blockDim.x;
  for (; i < E; i += stride) atomicAdd(&deg[row[i]], 1);
}

__global__ __launch_bounds__(256) void k_scan_blk(const int* __restrict__ in, int n,
    int* __restrict__ out, int* __restrict__ blksum){
  __shared__ int sm[256];
  const int tid = threadIdx.x;
  const int base = blockIdx.x * 1024;
  const int idx = base + tid * 4;
  int v0=0,v1=0,v2=0,v3=0;
  if (idx + 3 < n){ int4 t = *(const int4*)(in + idx); v0=t.x; v1=t.y; v2=t.z; v3=t.w; }
  else {
    if (idx   < n) v0 = in[idx];
    if (idx+1 < n) v1 = in[idx+1];
    if (idx+2 < n) v2 = in[idx+2];
    if (idx+3 < n) v3 = in[idx+3];
  }
  int s = v0+v1+v2+v3;
  sm[tid] = s; __syncthreads();
  for (int off = 1; off < 256; off <<= 1){
    int t = (tid >= off) ? sm[tid-off] : 0;
    __syncthreads();
    sm[tid] += t;
    __syncthreads();
  }
  int excl = sm[tid] - s;
  if (tid == 255) blksum[blockIdx.x] = sm[255];
  if (idx   < n) out[idx]   = excl;
  if (idx+1 < n) out[idx+1] = excl + v0;
  if (idx+2 < n) out[idx+2] = excl + v0 + v1;
  if (idx+3 < n) out[idx+3] = excl + v0 + v1 + v2;
}

__global__ __launch_bounds__(256) void k_scan_part(const int* __restrict__ blksum, int nblk,
    int* __restrict__ blkoff){
  __shared__ int sm[256];
  const int tid = threadIdx.x;
  int v = (tid < nblk) ? blksum[tid] : 0;
  sm[tid] = v; __syncthreads();
  for (int off = 1; off < 256; off <<= 1){
    int t = (tid >= off) ? sm[tid-off] : 0;
    __syncthreads();
    sm[tid] += t;
    __syncthreads();
  }
  if (tid < nblk) blkoff[tid] = sm[tid] - v;
}

__global__ __launch_bounds__(256) void k_scan_add(int* __restrict__ out, int n,
    const int* __restrict__ blkoff, int E){
  int i = blockIdx.x * 256 + threadIdx.x;
  if (i < n) out[i] += blkoff[i >> 10];
  if (i == 0) out[n] = E;
}

__global__ void k_fill_csr(const int* __restrict__ row, const int* __restrict__ col, int E,
                           const int* __restrict__ rowstart, int* __restrict__ cursor,
                           int* __restrict__ csrcol){
  int i = blockIdx.x * blockDim.x + threadIdx.x;
  int stride = gridDim.x * blockDim.x;
  for (; i < E; i += stride){
    int r = row[i];
    int pos = rowstart[r] + atomicAdd(&cursor[r], 1);
    csrcol[pos] = col[i];
  }
}

// ---------------- fused 3-output MFMA f16 GEMM: {Q,K,V} = X @ W{0,1,2}^T + b ----------------
__global__ __launch_bounds__(256) void k_qkv_mfma(const _Float16* __restrict__ X,
    const _Float16* __restrict__ W0, const float* __restrict__ b0, _Float16* __restrict__ Y0,
    const _Float16* __restrict__ W1, const float* __restrict__ b1, _Float16* __restrict__ Y1,
    const _Float16* __restrict__ W2, const float* __restrict__ b2, _Float16* __restrict__ Y2,
    int nrows)
{
  const int wid  = threadIdx.x >> 6;
  const int lane = threadIdx.x & 63;
  const int r0 = blockIdx.x * 64 + wid * 16;
  if (r0 >= nrows) return;
  const int l4 = lane & 15;
  const int kg = lane >> 4;
  int rA = r0 + l4; if (rA > nrows - 1) rA = nrows - 1;
  half8v a[4];
  #pragma unroll
  for (int ks = 0; ks < 4; ks++)
    a[ks] = *(const half8v*)(X + (size_t)rA * FD + ks*32 + kg*8);
  float4v acc0[8], acc1[8], acc2[8];
  #pragma unroll
  for (int t = 0; t < 8; t++)
    #pragma unroll
    for (int i = 0; i < 4; i++){ acc0[t][i] = 0.f; acc1[t][i] = 0.f; acc2[t][i] = 0.f; }
  #pragma unroll
  for (int t = 0; t < 8; t++){
    const int cB = t*16 + l4;
    #pragma unroll
    for (int ks = 0; ks < 4; ks++){
      half8v bb0 = *(const half8v*)(W0 + (size_t)cB * FD + ks*32 + kg*8);
      acc0[t] = __builtin_amdgcn_mfma_f32_16x16x32_f16(a[ks], bb0, acc0[t], 0, 0, 0);
      half8v bb1 = *(const half8v*)(W1 + (size_t)cB * FD + ks*32 + kg*8);
      acc1[t] = __builtin_amdgcn_mfma_f32_16x16x32_f16(a[ks], bb1, acc1[t], 0, 0, 0);
      half8v bb2 = *(const half8v*)(W2 + (size_t)cB * FD + ks*32 + kg*8);
      acc2[t] = __builtin_amdgcn_mfma_f32_16x16x32_f16(a[ks], bb2, acc2[t], 0, 0, 0);
    }
  }
  #pragma unroll
  for (int t = 0; t < 8; t++){
    const int c = t*16 + l4;
    const float bc0 = b0[c], bc1 = b1[c], bc2 = b2[c];
    #pragma unroll
    for (int i = 0; i < 4; i++){
      const int r = r0 + kg*4 + i;   // C/D: col=lane&15, row=(lane>>4)*4+reg [m89]
      if (r < nrows){
        Y0[(size_t)r * FD + c] = (_Float16)(acc0[t][i] + bc0);
        Y1[(size_t)r * FD + c] = (_Float16)(acc1[t][i] + bc1);
        Y2[(size_t)r * FD + c] = (_Float16)(acc2[t][i] + bc2);
      }
    }
  }
}

// ---------------- single-output MFMA f16 GEMM (ss path): Y = relu(X @ W^T + b) ----------------
template<int ACT, int OUTF32>
__global__ __launch_bounds__(256) void k_gemm_f16(const _Float16* __restrict__ X, int ldx,
    const _Float16* __restrict__ W, const float* __restrict__ bias,
    void* __restrict__ Y, int ldy, int nrows)
{
  const int wid  = threadIdx.x >> 6;
  const int lane = threadIdx.x & 63;
  const int r0 = blockIdx.x * 64 + wid * 16;
  if (r0 >= nrows) return;
  const int l4 = lane & 15;
  const int kg = lane >> 4;
  int rA = r0 + l4; if (rA > nrows - 1) rA = nrows - 1;
  half8v a[4];
  #pragma unroll
  for (int ks = 0; ks < 4; ks++)
    a[ks] = *(const half8v*)(X + (size_t)rA * ldx + ks*32 + kg*8);
  float4v acc[8];
  #pragma unroll
  for (int t = 0; t < 8; t++)
    #pragma unroll
    for (int i = 0; i < 4; i++) acc[t][i] = 0.f;
  #pragma unroll
  for (int t = 0; t < 8; t++){
    const int cB = t*16 + l4;
    #pragma unroll
    for (int ks = 0; ks < 4; ks++){
      half8v b = *(const half8v*)(W + (size_t)cB * FD + ks*32 + kg*8);
      acc[t] = __builtin_amdgcn_mfma_f32_16x16x32_f16(a[ks], b, acc[t], 0, 0, 0);
    }
  }
  #pragma unroll
  for (int t = 0; t < 8; t++){
    const int c = t*16 + l4;
    const float bc = bias[c];
    #pragma unroll
    for (int i = 0; i < 4; i++){
      const int r = r0 + kg*4 + i;
      if (r < nrows){
        float v = acc[t][i] + bc;
        if (ACT == 1) v = fmaxf(v, 0.f);
        if (OUTF32) ((float*)Y)[(size_t)r * ldy + c] = v;
        else        ((_Float16*)Y)[(size_t)r * ldy + c] = (_Float16)v;
      }
    }
  }
}

// ---------------- edge passes: 1 wave = 1 node, 32 lanes/row, 8 edges per half-wave ----------
#define RED5(d) \
  d += __shfl_xor(d, 16, 64); d += __shfl_xor(d, 8, 64); \
  d += __shfl_xor(d,  4, 64); d += __shfl_xor(d, 2, 64); d += __shfl_xor(d, 1, 64);

#define SC 0.08838834764831845f

static __device__ __forceinline__ float dot4h(const float4& q, half4v k){
  return q.x*(float)k[0] + q.y*(float)k[1] + q.z*(float)k[2] + q.w*(float)k[3];
}

// scores1 (Qh.Kh) fused with segment-mean of Xh -> SMh (fp16 strided)
__global__ __launch_bounds__(256) void k_passA(const _Float16* __restrict__ Qh, const _Float16* __restrict__ Kh,
    const _Float16* __restrict__ Xh, const int* __restrict__ rowstart, const int* __restrict__ csrcol,
    float* __restrict__ scores, _Float16* __restrict__ SMh, int ldsm, int nnodes)
{
  const int n = blockIdx.x * 4 + (threadIdx.x >> 6);
  if (n >= nnodes) return;
  const int lane = threadIdx.x & 63, l5 = lane & 31, h = lane >> 5;
  half4v qu = *(const half4v*)(Qh + (unsigned)n * FD + 4*l5);
  const float4 q = make_float4((float)qu[0], (float)qu[1], (float)qu[2], (float)qu[3]);
  float4 sx = make_float4(0.f, 0.f, 0.f, 0.f);
  const int p0 = rowstart[n], p1 = rowstart[n+1];
  const int last = p1 - 1;
  for (int p = p0; p < p1; p += 16){
    int idx[8], cc[8];
    #pragma unroll
    for (int k = 0; k < 8; k++){
      idx[k] = p + 2*k + h;
      cc[k] = csrcol[idx[k] < p1 ? idx[k] : last];
    }
    half4v kv[8], xv[8];
    #pragma unroll
    for (int k = 0; k < 8; k++){
      kv[k] = *(const half4v*)(Kh + (unsigned)cc[k]*FD + 4*l5);
      xv[k] = *(const half4v*)(Xh + (unsigned)cc[k]*FD + 4*l5);
    }
    float d[8];
    #pragma unroll
    for (int k = 0; k < 8; k++){
      d[k] = dot4h(q, kv[k]);
      const float m = idx[k] < p1 ? 1.f : 0.f;
      sx.x += m*(float)xv[k][0]; sx.y += m*(float)xv[k][1];
      sx.z += m*(float)xv[k][2]; sx.w += m*(float)xv[k][3];
    }
    #pragma unroll
    for (int k = 0; k < 8; k++){ RED5(d[k]) }
    if (l5 == 0){
      #pragma unroll
      for (int k = 0; k < 8; k++)
        if (idx[k] < p1) scores[idx[k]] = d[k] * SC;
    }
  }
  sx.x += __shfl_xor(sx.x, 32, 64); sx.y += __shfl_xor(sx.y, 32, 64);
  sx.z += __shfl_xor(sx.z, 32, 64); sx.w += __shfl_xor(sx.w, 32, 64);
  int dg = p1 - p0; if (dg < 1) dg = 1;
  const float inv = 1.f / (float)dg;
  if (h == 0){
    half4v o;
    o[0] = (_Float16)(sx.x*inv); o[1] = (_Float16)(sx.y*inv);
    o[2] = (_Float16)(sx.z*inv); o[3] = (_Float16)(sx.w*inv);
    *(half4v*)(SMh + (size_t)n * ldsm + 4*l5) = o;
  }
}

// scores (layer 2)
__global__ __launch_bounds__(256) void k_scores2(const _Float16* __restrict__ Qh, const _Float16* __restrict__ Kh,
    const int* __restrict__ rowstart, const int* __restrict__ csrcol,
    float* __restrict__ scores, int nnodes)
{
  const int n = blockIdx.x * 4 + (threadIdx.x >> 6);
  if (n >= nnodes) return;
  const int lane = threadIdx.x & 63, l5 = lane & 31, h = lane >> 5;
  const int p0 = rowstart[n], p1 = rowstart[n+1];
  if (p0 >= p1) return;
  half4v qu = *(const half4v*)(Qh + (unsigned)n * FD + 4*l5);
  const float4 q = make_float4((float)qu[0], (float)qu[1], (float)qu[2], (float)qu[3]);
  const int last = p1 - 1;
  for (int p = p0; p < p1; p += 16){
    int idx[8], cc[8];
    #pragma unroll
    for (int k = 0; k < 8; k++){
      idx[k] = p + 2*k + h;
      cc[k] = csrcol[idx[k] < p1 ? idx[k] : last];
    }
    half4v kv[8];
    #pragma unroll
    for (int k = 0; k < 8; k++) kv[k] = *(const half4v*)(Kh + (unsigned)cc[k]*FD + 4*l5);
    float d[8];
    #pragma unroll
    for (int k = 0; k < 8; k++) d[k] = dot4h(q, kv[k]);
    #pragma unroll
    for (int k = 0; k < 8; k++){ RED5(d[k]) }
    if (l5 == 0){
      #pragma unroll
      for (int k = 0; k < 8; k++)
        if (idx[k] < p1) scores[idx[k]] = d[k] * SC;
    }
  }
}

// message1 (alpha-weighted Vh, ELU -> Ah fp16) fused with segment-mean of Sh -> Bh (fp16 strided)
__global__ __launch_bounds__(256) void k_passB(const _Float16* __restrict__ Vh, const _Float16* __restrict__ Sh,
    const float* __restrict__ sc, const float* __restrict__ Mp, const float* __restrict__ Ip,
    const int* __restrict__ rowstart, const int* __restrict__ csrcol,
    _Float16* __restrict__ Ah, _Float16* __restrict__ Bh, int ldb, int nnodes)
{
  const int n = blockIdx.x * 4 + (threadIdx.x >> 6);
  if (n >= nnodes) return;
  const int lane = threadIdx.x & 63, l5 = lane & 31, h = lane >> 5;
  const float M = Mp[0], inv = Ip[0];
  float4 av = make_float4(0.f, 0.f, 0.f, 0.f);
  float4 sv = make_float4(0.f, 0.f, 0.f, 0.f);
  const int p0 = rowstart[n], p1 = rowstart[n+1];
  const int last = p1 - 1;
  for (int p = p0; p < p1; p += 16){
    int idx[8], cc[8]; float aa[8];
    #pragma unroll
    for (int k = 0; k < 8; k++){
      idx[k] = p + 2*k + h;
      const int eff = idx[k] < p1 ? idx[k] : last;
      cc[k] = csrcol[eff];
      aa[k] = sc[eff];
    }
    half4v vv[8], ss[8];
    #pragma unroll
    for (int k = 0; k < 8; k++){
      vv[k] = *(const half4v*)(Vh + (unsigned)cc[k]*FD + 4*l5);
      ss[k] = *(const half4v*)(Sh + (unsigned)cc[k]*FD + 4*l5);
    }
    #pragma unroll
    for (int k = 0; k < 8; k++){
      const float m = idx[k] < p1 ? 1.f : 0.f;
      const float a = m * __expf(aa[k] - M);
      av.x += a*(float)vv[k][0]; av.y += a*(float)vv[k][1];
      av.z += a*(float)vv[k][2]; av.w += a*(float)vv[k][3];
      sv.x += m*(float)ss[k][0]; sv.y += m*(float)ss[k][1];
      sv.z += m*(float)ss[k][2]; sv.w += m*(float)ss[k][3];
    }
  }
  av.x += __shfl_xor(av.x, 32, 64); av.y += __shfl_xor(av.y, 32, 64);
  av.z += __shfl_xor(av.z, 32, 64); av.w += __shfl_xor(av.w, 32, 64);
  sv.x += __shfl_xor(sv.x, 32, 64); sv.y += __shfl_xor(sv.y, 32, 64);
  sv.z += __shfl_xor(sv.z, 32, 64); sv.w += __shfl_xor(sv.w, 32, 64);
  if (h == 0){
    av.x *= inv; av.y *= inv; av.z *= inv; av.w *= inv;
    av.x = av.x > 0.f ? av.x : expm1f(av.x);
    av.y = av.y > 0.f ? av.y : expm1f(av.y);
    av.z = av.z > 0.f ? av.z : expm1f(av.z);
    av.w = av.w > 0.f ? av.w : expm1f(av.w);
    half4v oa;
    oa[0] = (_Float16)av.x; oa[1] = (_Float16)av.y; oa[2] = (_Float16)av.z; oa[3] = (_Float16)av.w;
    *(half4v*)(Ah + (unsigned)n * FD + 4*l5) = oa;
    int dg = p1 - p0; if (dg < 1) dg = 1;
    const float invd = 1.f / (float)dg;
    half4v ob;
    ob[0] = (_Float16)(sv.x*invd); ob[1] = (_Float16)(sv.y*invd);
    ob[2] = (_Float16)(sv.z*invd); ob[3] = (_Float16)(sv.w*invd);
    *(half4v*)(Bh + (size_t)n * ldb + 4*l5) = ob;
  }
}

// message2 -> out (fp32)
__global__ __launch_bounds__(256) void k_message2(const _Float16* __restrict__ Vh,
    const float* __restrict__ sc, const float* __restrict__ Mp, const float* __restrict__ Ip,
    const int* __restrict__ rowstart, const int* __restrict__ csrcol,
    float4* __restrict__ out4, int ldo4, int nnodes)
{
  const int n = blockIdx.x * 4 + (threadIdx.x >> 6);
  if (n >= nnodes) return;
  const int lane = threadIdx.x & 63, l5 = lane & 31, h = lane >> 5;
  const float M = Mp[0], inv = Ip[0];
  float4 av = make_float4(0.f, 0.f, 0.f, 0.f);
  const int p0 = rowstart[n], p1 = rowstart[n+1];
  const int last = p1 - 1;
  for (int p = p0; p < p1; p += 16){
    int idx[8], cc[8]; float aa[8];
    #pragma unroll
    for (int k = 0; k < 8; k++){
      idx[k] = p + 2*k + h;
      const int eff = idx[k] < p1 ? idx[k] : last;
      cc[k] = csrcol[eff];
      aa[k] = sc[eff];
    }
    half4v vv[8];
    #pragma unroll
    for (int k = 0; k < 8; k++) vv[k] = *(const half4v*)(Vh + (unsigned)cc[k]*FD + 4*l5);
    #pragma unroll
    for (int k = 0; k < 8; k++){
      const float m = idx[k] < p1 ? 1.f : 0.f;
      const float a = m * __expf(aa[k] - M);
      av.x += a*(float)vv[k][0]; av.y += a*(float)vv[k][1];
      av.z += a*(float)vv[k][2]; av.w += a*(float)vv[k][3];
    }
  }
  av.x += __shfl_xor(av.x, 32, 64); av.y += __shfl_xor(av.y, 32, 64);
  av.z += __shfl_xor(av.z, 32, 64); av.w += __shfl_xor(av.w, 32, 64);
  if (h == 0)
    out4[(unsigned)n * ldo4 + l5] = make_float4(av.x*inv, av.y*inv, av.z*inv, av.w*inv);
}

// ---------------- fused online softmax reductions ----------------
__global__ __launch_bounds__(256) void k_sm_partial(const float* __restrict__ s, int n,
    float* __restrict__ pm, float* __restrict__ ps){
  __shared__ float sm_m[256], sm_s[256];
  const int tid = threadIdx.x;
  float m = -3.402823466e38f, sum = 0.f;
  for (int i = blockIdx.x * 256 + tid; i < n; i += gridDim.x * 256){
    float v = s[i];
    if (v <= m) sum += __expf(v - m);
    else { sum = sum * __expf(m - v) + 1.f; m = v; }
  }
  sm_m[tid] = m; sm_s[tid] = sum; __syncthreads();
  for (int off = 128; off > 0; off >>= 1){
    if (tid < off){
      float m2 = sm_m[tid + off], s2 = sm_s[tid + off];
      float m1 = sm_m[tid], s1 = sm_s[tid];
      float Mx = fmaxf(m1, m2);
      sm_m[tid] = Mx;
      sm_s[tid] = s1 * __expf(m1 - Mx) + s2 * __expf(m2 - Mx);
    }
    __syncthreads();
  }
  if (tid == 0){ pm[blockIdx.x] = sm_m[0]; ps[blockIdx.x] = sm_s[0]; }
}

__global__ __launch_bounds__(256) void k_sm_final(const float* __restrict__ pm, const float* __restrict__ ps,
    int n, float* __restrict__ Mout, float* __restrict__ Iout){
  __shared__ float sm_m[256], sm_s[256];
  const int tid = threadIdx.x;
  float m = -3.402823466e38f, sum = 0.f;
  for (int i = tid; i < n; i += 256){
    float m2 = pm[i], s2 = ps[i];
    float Mx = fmaxf(m, m2);
    sum = sum * __expf(m - Mx) + s2 * __expf(m2 - Mx);
    m = Mx;
  }
  sm_m[tid] = m; sm_s[tid] = sum; __syncthreads();
  for (int off = 128; off > 0; off >>= 1){
    if (tid < off){
      float m2 = sm_m[tid + off], s2 = sm_s[tid + off];
      float m1 = sm_m[tid], s1 = sm_s[tid];
      float Mx = fmaxf(m1, m2);
      sm_m[tid] = Mx;
      sm_s[tid] = s1 * __expf(m1 - Mx) + s2 * __expf(m2 - Mx);
    }
    __syncthreads();
  }
  if (tid == 0){ Mout[0] = sm_m[0]; Iout[0] = 1.f / sm_s[0]; }
}

extern "C" void kernel_launch(void* const* d_in, const int* in_sizes, int n_in,
                              void* d_out, int out_size, void* d_ws, size_t ws_size,
                              hipStream_t stream)
{
  const float* x   = (const float*)d_in[0];
  const int*   ei  = (const int*)d_in[1];
  const float* Wq1 = (const float*)d_in[2];  const float* bq1 = (const float*)d_in[3];
  const float* Wk1 = (const float*)d_in[4];  const float* bk1 = (const float*)d_in[5];
  const float* Wv1 = (const float*)d_in[6];  const float* bv1 = (const float*)d_in[7];
  const float* Wq2 = (const float*)d_in[8];  const float* bq2 = (const float*)d_in[9];
  const float* Wk2 = (const float*)d_in[10]; const float* bk2 = (const float*)d_in[11];
  const float* Wv2 = (const float*)d_in[12]; const float* bv2 = (const float*)d_in[13];
  const float* Ws1 = (const float*)d_in[14]; const float* bs1 = (const float*)d_in[15];
  const float* Ws2 = (const float*)d_in[16]; const float* bs2 = (const float*)d_in[17];

  const int N = in_sizes[0] / FD;
  const int E = in_sizes[1] / 2;
  const int* row = ei;
  const int* col = ei + E;
  float* out = (float*)d_out;

  char* ws = (char*)d_ws;
  size_t off = 0;
  auto alloc = [&](size_t bytes) -> void* {
    void* p = ws + off;
    off += (bytes + 255) & ~(size_t)255;
    return p;
  };
  int* deg      = (int*)alloc((size_t)N * 4);
  int* rowstart = (int*)alloc((size_t)(N + 1) * 4);
  int* cursor   = (int*)alloc((size_t)N * 4);
  int* csrcol   = (int*)alloc((size_t)E * 4);
  float* scores = (float*)alloc((size_t)E * 4);
  int* blksum   = (int*)alloc(1024);
  int* blkoff   = (int*)alloc(1024);
  float* pm     = (float*)alloc(1024);
  float* ps     = (float*)alloc(1024);
  float* Mv     = (float*)alloc(256);
  float* Iv     = (float*)alloc(256);
  _Float16* Xh = (_Float16*)alloc((size_t)N * FD * 2);   // x fp16; aliased as Sh after passA+GEMM1 start
  _Float16* Qh = (_Float16*)alloc((size_t)N * FD * 2);
  _Float16* Kh = (_Float16*)alloc((size_t)N * FD * 2);
  _Float16* Vh = (_Float16*)alloc((size_t)N * FD * 2);
  _Float16* Ah = (_Float16*)alloc((size_t)N * FD * 2);
  _Float16* Wh = (_Float16*)alloc((size_t)8 * FD * FD * 2);
  _Float16* Sh = Xh;                 // s1: Xh dead after passA (QKV1 + passA both done)
  _Float16* SMBh = (_Float16*)out;   // seg-mean scratch inside out cols[0,128) bytes, ld 512 halfs
  (void)ws_size; (void)n_in; (void)out_size;

  hipMemsetAsync(deg, 0, (size_t)N * 4, stream);
  hipMemsetAsync(cursor, 0, (size_t)N * 4, stream);

  // conversions
  k_cvt_x<<<2048, 256, 0, stream>>>((const float4*)x, (half4v*)Xh, N * FD / 4);
  k_cvt_w<<<(FD*FD + 255)/256, 256, 0, stream>>>(Wq1, Wk1, Wv1, Wq2, Wk2, Wv2, Ws1, Ws2, Wh);

  // CSR
  const int eb = 2048;
  const int nblk = (N + 1023) / 1024;
  k_count_deg<<<eb, 256, 0, stream>>>(row, E, deg);
  k_scan_blk<<<nblk, 256, 0, stream>>>(deg, N, rowstart, blksum);
  k_scan_part<<<1, 256, 0, stream>>>(blksum, nblk, blkoff);
  k_scan_add<<<(N + 255)/256, 256, 0, stream>>>(rowstart, N, blkoff, E);
  k_fill_csr<<<eb, 256, 0, stream>>>(row, col, E, rowstart, cursor, csrcol);

  const int gb = (N + 63) / 64;
  const int nb = (N + 3) / 4;
  const int rb = 256;

  // ---- layer-1 QKV (fused MFMA f16) ----
  k_qkv_mfma<<<gb, 256, 0, stream>>>(Xh, Wh + 0*FD*FD, bq1, Qh,
                                          Wh + 1*FD*FD, bk1, Kh,
                                          Wh + 2*FD*FD, bv1, Vh, N);

  // ---- fused: scores1 + seg_mean(Xh) -> SMBh (fp16 in out, ld 512) ----
  k_passA<<<nb, 256, 0, stream>>>(Qh, Kh, Xh, rowstart, csrcol, scores, SMBh, 512, N);

  k_sm_partial<<<rb, 256, 0, stream>>>(scores, E, pm, ps);
  k_sm_final<<<1, 256, 0, stream>>>(pm, ps, rb, Mv, Iv);

  // s1 = relu(SMBh @ Ws1^T + bs1) -> Sh (fp16 packed; overwrites dead Xh)
  k_gemm_f16<1,0><<<gb, 256, 0, stream>>>(SMBh, 512, Wh + 6*FD*FD, bs1, Sh, FD, N);

  // ---- fused: message1+ELU -> Ah; seg_mean(s1) -> Bh (= SMBh region, SM dead) ----
  k_passB<<<nb, 256, 0, stream>>>(Vh, Sh, scores, Mv, Iv, rowstart, csrcol, Ah, SMBh, 512, N);

  // ss_out = relu(Bh @ Ws2^T + bs2) -> out cols [128,256) fp32
  k_gemm_f16<1,1><<<gb, 256, 0, stream>>>(SMBh, 512, Wh + 7*FD*FD, bs2, out + FD, 2*FD, N);

  // ---- layer-2 QKV (fused MFMA f16; overwrites Qh/Kh/Vh after passB consumed Vh) ----
  k_qkv_mfma<<<gb, 256, 0, stream>>>(Ah, Wh + 3*FD*FD, bq2, Qh,
                                         Wh + 4*FD*FD, bk2, Kh,
                                         Wh + 5*FD*FD, bv2, Vh, N);
  k_scores2<<<nb, 256, 0, stream>>>(Qh, Kh, rowstart, csrcol, scores, N);

  k_sm_partial<<<rb, 256, 0, stream>>>(scores, E, pm, ps);
  k_sm_final<<<1, 256, 0, stream>>>(pm, ps, rb, Mv, Iv);

  // message2 -> out cols [0,128) fp32 (overwrites Bh region only after GEMM2 consumed it)
  k_message2<<<nb, 256, 0, stream>>>(Vh, scores, Mv, Iv, rowstart, csrcol, (float4*)out, 64, N);
}

// Round 6
// 386.907 us; speedup vs baseline: 3.3557x; 1.2575x over previous
//
#include <hip/hip_runtime.h>
#include <math.h>

#define FD 128

typedef __attribute__((ext_vector_type(8))) _Float16 half8v;
typedef __attribute__((ext_vector_type(4))) _Float16 half4v;
typedef __attribute__((ext_vector_type(4))) float float4v;

// ---------------- conversions ----------------
__global__ void k_cvt_x(const float4* __restrict__ in, half4v* __restrict__ out, int n4){
  int i = blockIdx.x * 256 + threadIdx.x, st = gridDim.x * 256;
  for (; i < n4; i += st){
    float4 v = in[i];
    half4v o;
    o[0] = (_Float16)v.x; o[1] = (_Float16)v.y; o[2] = (_Float16)v.z; o[3] = (_Float16)v.w;
    out[i] = o;
  }
}

__global__ __launch_bounds__(256) void k_cvt_w(
    const float* __restrict__ w0, const float* __restrict__ w1, const float* __restrict__ w2,
    const float* __restrict__ w3, const float* __restrict__ w4, const float* __restrict__ w5,
    const float* __restrict__ w6, const float* __restrict__ w7, _Float16* __restrict__ dst){
  int i = blockIdx.x * 256 + threadIdx.x;
  if (i >= FD * FD) return;
  dst[0*FD*FD + i] = (_Float16)w0[i];
  dst[1*FD*FD + i] = (_Float16)w1[i];
  dst[2*FD*FD + i] = (_Float16)w2[i];
  dst[3*FD*FD + i] = (_Float16)w3[i];
  dst[4*FD*FD + i] = (_Float16)w4[i];
  dst[5*FD*FD + i] = (_Float16)w5[i];
  dst[6*FD*FD + i] = (_Float16)w6[i];
  dst[7*FD*FD + i] = (_Float16)w7[i];
}

// ---------------- CSR build ----------------
__global__ void k_count_deg(const int* __restrict__ row, int E, int* __restrict__ deg){
  int i = blockIdx.x * blockDim.x + threadIdx.x;
  int stride = gridDim.x * blockDim.x;
  for (; i < E; i += stride) atomicAdd(&deg[row[i]], 1);
}

__global__ __launch_bounds__(256) void k_scan_blk(const int* __restrict__ in, int n,
    int* __restrict__ out, int* __restrict__ blksum){
  __shared__ int sm[256];
  const int tid = threadIdx.x;
  const int base = blockIdx.x * 1024;
  const int idx = base + tid * 4;
  int v0=0,v1=0,v2=0,v3=0;
  if (idx + 3 < n){ int4 t = *(const int4*)(in + idx); v0=t.x; v1=t.y; v2=t.z; v3=t.w; }
  else {
    if (idx   < n) v0 = in[idx];
    if (idx+1 < n) v1 = in[idx+1];
    if (idx+2 < n) v2 = in[idx+2];
    if (idx+3 < n) v3 = in[idx+3];
  }
  int s = v0+v1+v2+v3;
  sm[tid] = s; __syncthreads();
  for (int off = 1; off < 256; off <<= 1){
    int t = (tid >= off) ? sm[tid-off] : 0;
    __syncthreads();
    sm[tid] += t;
    __syncthreads();
  }
  int excl = sm[tid] - s;
  if (tid == 255) blksum[blockIdx.x] = sm[255];
  if (idx   < n) out[idx]   = excl;
  if (idx+1 < n) out[idx+1] = excl + v0;
  if (idx+2 < n) out[idx+2] = excl + v0 + v1;
  if (idx+3 < n) out[idx+3] = excl + v0 + v1 + v2;
}

__global__ __launch_bounds__(256) void k_scan_part(const int* __restrict__ blksum, int nblk,
    int* __restrict__ blkoff){
  __shared__ int sm[256];
  const int tid = threadIdx.x;
  int v = (tid < nblk) ? blksum[tid] : 0;
  sm[tid] = v; __syncthreads();
  for (int off = 1; off < 256; off <<= 1){
    int t = (tid >= off) ? sm[tid-off] : 0;
    __syncthreads();
    sm[tid] += t;
    __syncthreads();
  }
  if (tid < nblk) blkoff[tid] = sm[tid] - v;
}

__global__ __launch_bounds__(256) void k_scan_add(int* __restrict__ out, int n,
    const int* __restrict__ blkoff, int E){
  int i = blockIdx.x * 256 + threadIdx.x;
  if (i < n) out[i] += blkoff[i >> 10];
  if (i == 0) out[n] = E;
}

__global__ void k_fill_csr(const int* __restrict__ row, const int* __restrict__ col, int E,
                           const int* __restrict__ rowstart, int* __restrict__ cursor,
                           int* __restrict__ csrcol){
  int i = blockIdx.x * blockDim.x + threadIdx.x;
  int stride = gridDim.x * blockDim.x;
  for (; i < E; i += stride){
    int r = row[i];
    int pos = rowstart[r] + atomicAdd(&cursor[r], 1);
    csrcol[pos] = col[i];
  }
}

// ---------------- LDS-staged MFMA f16 GEMM (1..3 outputs) ----------------
// Per block: 64 rows x 128 cols. W staged in LDS (one output at a time, XOR-swizzled).
// Operands swapped (A=W-frag, B=X-frag) so each lane owns 4 consecutive output cols
// of ONE row -> coalesced vector stores.  C/D map: D-row <-> A-lane, D-col <-> B-lane.
template<int NOUT, int ACT, int OUTF32>
__global__ __launch_bounds__(256) void k_gemm_lds(const _Float16* __restrict__ X, int ldx,
    const _Float16* __restrict__ W,
    const float* __restrict__ b0, void* __restrict__ Y0,
    const float* __restrict__ b1, _Float16* __restrict__ Y1,
    const float* __restrict__ b2, _Float16* __restrict__ Y2,
    int ldy, int nrows)
{
  __shared__ _Float16 sW[FD * FD];    // 32 KB
  const int tid  = threadIdx.x;
  const int wid  = tid >> 6;
  const int lane = tid & 63;
  const int l4 = lane & 15;
  const int kg = lane >> 4;
  const int r0 = blockIdx.x * 64 + wid * 16;

  int rA = r0 + l4; if (rA > nrows - 1) rA = nrows - 1;
  half8v xf[4];
  #pragma unroll
  for (int ks = 0; ks < 4; ks++)
    xf[ks] = *(const half8v*)(X + (size_t)rA * ldx + ks*32 + kg*8);

  for (int o = 0; o < NOUT; o++){
    if (o) __syncthreads();
    const _Float16* Wo = W + (size_t)o * FD * FD;
    #pragma unroll
    for (int j = 0; j < 8; j++){
      const int b = j*4096 + tid*16;        // linear byte 0..32767 (coalesced 16B/lane)
      const int row = b >> 8, cb = b & 255;
      half8v v = *(const half8v*)((const char*)Wo + b);
      *(half8v*)((char*)sW + ((row*256 + (cb ^ ((row & 7) << 4))))) = v;
    }
    __syncthreads();

    float4v acc[8];
    #pragma unroll
    for (int t = 0; t < 8; t++)
      #pragma unroll
      for (int i = 0; i < 4; i++) acc[t][i] = 0.f;

    #pragma unroll
    for (int t = 0; t < 8; t++){
      const int row = t*16 + l4;            // W row (output col block)
      const int sw = (row & 7) << 4;
      #pragma unroll
      for (int ks = 0; ks < 4; ks++){
        half8v wf = *(const half8v*)((const char*)sW + (row*256 + ((ks*64 + kg*16) ^ sw)));
        acc[t] = __builtin_amdgcn_mfma_f32_16x16x32_f16(wf, xf[ks], acc[t], 0, 0, 0);
      }
    }

    const float* bo = (o == 0) ? b0 : (o == 1) ? b1 : b2;
    const int r = r0 + l4;
    if (r < nrows){
      #pragma unroll
      for (int t = 0; t < 8; t++){
        const int c = t*16 + kg*4;
        const float4 bb = *(const float4*)(bo + c);
        float v0 = acc[t][0] + bb.x, v1 = acc[t][1] + bb.y;
        float v2 = acc[t][2] + bb.z, v3 = acc[t][3] + bb.w;
        if (ACT){ v0=fmaxf(v0,0.f); v1=fmaxf(v1,0.f); v2=fmaxf(v2,0.f); v3=fmaxf(v3,0.f); }
        if (OUTF32 && o == 0){
          *(float4*)((float*)Y0 + (size_t)r * ldy + c) = make_float4(v0, v1, v2, v3);
        } else {
          _Float16* Yo = (o == 0) ? (_Float16*)Y0 : (o == 1) ? Y1 : Y2;
          half4v hv;
          hv[0]=(_Float16)v0; hv[1]=(_Float16)v1; hv[2]=(_Float16)v2; hv[3]=(_Float16)v3;
          *(half4v*)(Yo + (size_t)r * ldy + c) = hv;
        }
      }
    }
  }
}

// ---------------- edge passes: 1 wave = 1 node, 32 lanes/row, 8 edges per half-wave ----------
#define RED5(d) \
  d += __shfl_xor(d, 16, 64); d += __shfl_xor(d, 8, 64); \
  d += __shfl_xor(d,  4, 64); d += __shfl_xor(d, 2, 64); d += __shfl_xor(d, 1, 64);

#define SC 0.08838834764831845f

static __device__ __forceinline__ float dot4h(const float4& q, half4v k){
  return q.x*(float)k[0] + q.y*(float)k[1] + q.z*(float)k[2] + q.w*(float)k[3];
}

// scores1 (Qh.Kh) fused with segment-mean of Xh -> SMh (fp16 strided)
__global__ __launch_bounds__(256) void k_passA(const _Float16* __restrict__ Qh, const _Float16* __restrict__ Kh,
    const _Float16* __restrict__ Xh, const int* __restrict__ rowstart, const int* __restrict__ csrcol,
    float* __restrict__ scores, _Float16* __restrict__ SMh, int ldsm, int nnodes)
{
  const int n = blockIdx.x * 4 + (threadIdx.x >> 6);
  if (n >= nnodes) return;
  const int lane = threadIdx.x & 63, l5 = lane & 31, h = lane >> 5;
  half4v qu = *(const half4v*)(Qh + (unsigned)n * FD + 4*l5);
  const float4 q = make_float4((float)qu[0], (float)qu[1], (float)qu[2], (float)qu[3]);
  float4 sx = make_float4(0.f, 0.f, 0.f, 0.f);
  const int p0 = rowstart[n], p1 = rowstart[n+1];
  const int last = p1 - 1;
  for (int p = p0; p < p1; p += 16){
    int idx[8], cc[8];
    #pragma unroll
    for (int k = 0; k < 8; k++){
      idx[k] = p + 2*k + h;
      cc[k] = csrcol[idx[k] < p1 ? idx[k] : last];
    }
    half4v kv[8], xv[8];
    #pragma unroll
    for (int k = 0; k < 8; k++){
      kv[k] = *(const half4v*)(Kh + (unsigned)cc[k]*FD + 4*l5);
      xv[k] = *(const half4v*)(Xh + (unsigned)cc[k]*FD + 4*l5);
    }
    float d[8];
    #pragma unroll
    for (int k = 0; k < 8; k++){
      d[k] = dot4h(q, kv[k]);
      const float m = idx[k] < p1 ? 1.f : 0.f;
      sx.x += m*(float)xv[k][0]; sx.y += m*(float)xv[k][1];
      sx.z += m*(float)xv[k][2]; sx.w += m*(float)xv[k][3];
    }
    #pragma unroll
    for (int k = 0; k < 8; k++){ RED5(d[k]) }
    if (l5 == 0){
      #pragma unroll
      for (int k = 0; k < 8; k++)
        if (idx[k] < p1) scores[idx[k]] = d[k] * SC;
    }
  }
  sx.x += __shfl_xor(sx.x, 32, 64); sx.y += __shfl_xor(sx.y, 32, 64);
  sx.z += __shfl_xor(sx.z, 32, 64); sx.w += __shfl_xor(sx.w, 32, 64);
  int dg = p1 - p0; if (dg < 1) dg = 1;
  const float inv = 1.f / (float)dg;
  if (h == 0){
    half4v o;
    o[0] = (_Float16)(sx.x*inv); o[1] = (_Float16)(sx.y*inv);
    o[2] = (_Float16)(sx.z*inv); o[3] = (_Float16)(sx.w*inv);
    *(half4v*)(SMh + (size_t)n * ldsm + 4*l5) = o;
  }
}

// scores (layer 2)
__global__ __launch_bounds__(256) void k_scores2(const _Float16* __restrict__ Qh, const _Float16* __restrict__ Kh,
    const int* __restrict__ rowstart, const int* __restrict__ csrcol,
    float* __restrict__ scores, int nnodes)
{
  const int n = blockIdx.x * 4 + (threadIdx.x >> 6);
  if (n >= nnodes) return;
  const int lane = threadIdx.x & 63, l5 = lane & 31, h = lane >> 5;
  const int p0 = rowstart[n], p1 = rowstart[n+1];
  if (p0 >= p1) return;
  half4v qu = *(const half4v*)(Qh + (unsigned)n * FD + 4*l5);
  const float4 q = make_float4((float)qu[0], (float)qu[1], (float)qu[2], (float)qu[3]);
  const int last = p1 - 1;
  for (int p = p0; p < p1; p += 16){
    int idx[8], cc[8];
    #pragma unroll
    for (int k = 0; k < 8; k++){
      idx[k] = p + 2*k + h;
      cc[k] = csrcol[idx[k] < p1 ? idx[k] : last];
    }
    half4v kv[8];
    #pragma unroll
    for (int k = 0; k < 8; k++) kv[k] = *(const half4v*)(Kh + (unsigned)cc[k]*FD + 4*l5);
    float d[8];
    #pragma unroll
    for (int k = 0; k < 8; k++) d[k] = dot4h(q, kv[k]);
    #pragma unroll
    for (int k = 0; k < 8; k++){ RED5(d[k]) }
    if (l5 == 0){
      #pragma unroll
      for (int k = 0; k < 8; k++)
        if (idx[k] < p1) scores[idx[k]] = d[k] * SC;
    }
  }
}

// message1 (alpha-weighted Vh, ELU -> Ah fp16) fused with segment-mean of Sh -> Bh (fp16 strided)
__global__ __launch_bounds__(256) void k_passB(const _Float16* __restrict__ Vh, const _Float16* __restrict__ Sh,
    const float* __restrict__ sc, const float* __restrict__ Mp, const float* __restrict__ Ip,
    const int* __restrict__ rowstart, const int* __restrict__ csrcol,
    _Float16* __restrict__ Ah, _Float16* __restrict__ Bh, int ldb, int nnodes)
{
  const int n = blockIdx.x * 4 + (threadIdx.x >> 6);
  if (n >= nnodes) return;
  const int lane = threadIdx.x & 63, l5 = lane & 31, h = lane >> 5;
  const float M = Mp[0], inv = Ip[0];
  float4 av = make_float4(0.f, 0.f, 0.f, 0.f);
  float4 sv = make_float4(0.f, 0.f, 0.f, 0.f);
  const int p0 = rowstart[n], p1 = rowstart[n+1];
  const int last = p1 - 1;
  for (int p = p0; p < p1; p += 16){
    int idx[8], cc[8]; float aa[8];
    #pragma unroll
    for (int k = 0; k < 8; k++){
      idx[k] = p + 2*k + h;
      const int eff = idx[k] < p1 ? idx[k] : last;
      cc[k] = csrcol[eff];
      aa[k] = sc[eff];
    }
    half4v vv[8], ss[8];
    #pragma unroll
    for (int k = 0; k < 8; k++){
      vv[k] = *(const half4v*)(Vh + (unsigned)cc[k]*FD + 4*l5);
      ss[k] = *(const half4v*)(Sh + (unsigned)cc[k]*FD + 4*l5);
    }
    #pragma unroll
    for (int k = 0; k < 8; k++){
      const float m = idx[k] < p1 ? 1.f : 0.f;
      const float a = m * __expf(aa[k] - M);
      av.x += a*(float)vv[k][0]; av.y += a*(float)vv[k][1];
      av.z += a*(float)vv[k][2]; av.w += a*(float)vv[k][3];
      sv.x += m*(float)ss[k][0]; sv.y += m*(float)ss[k][1];
      sv.z += m*(float)ss[k][2]; sv.w += m*(float)ss[k][3];
    }
  }
  av.x += __shfl_xor(av.x, 32, 64); av.y += __shfl_xor(av.y, 32, 64);
  av.z += __shfl_xor(av.z, 32, 64); av.w += __shfl_xor(av.w, 32, 64);
  sv.x += __shfl_xor(sv.x, 32, 64); sv.y += __shfl_xor(sv.y, 32, 64);
  sv.z += __shfl_xor(sv.z, 32, 64); sv.w += __shfl_xor(sv.w, 32, 64);
  if (h == 0){
    av.x *= inv; av.y *= inv; av.z *= inv; av.w *= inv;
    av.x = av.x > 0.f ? av.x : expm1f(av.x);
    av.y = av.y > 0.f ? av.y : expm1f(av.y);
    av.z = av.z > 0.f ? av.z : expm1f(av.z);
    av.w = av.w > 0.f ? av.w : expm1f(av.w);
    half4v oa;
    oa[0] = (_Float16)av.x; oa[1] = (_Float16)av.y; oa[2] = (_Float16)av.z; oa[3] = (_Float16)av.w;
    *(half4v*)(Ah + (unsigned)n * FD + 4*l5) = oa;
    int dg = p1 - p0; if (dg < 1) dg = 1;
    const float invd = 1.f / (float)dg;
    half4v ob;
    ob[0] = (_Float16)(sv.x*invd); ob[1] = (_Float16)(sv.y*invd);
    ob[2] = (_Float16)(sv.z*invd); ob[3] = (_Float16)(sv.w*invd);
    *(half4v*)(Bh + (size_t)n * ldb + 4*l5) = ob;
  }
}

// message2 -> out (fp32)
__global__ __launch_bounds__(256) void k_message2(const _Float16* __restrict__ Vh,
    const float* __restrict__ sc, const float* __restrict__ Mp, const float* __restrict__ Ip,
    const int* __restrict__ rowstart, const int* __restrict__ csrcol,
    float4* __restrict__ out4, int ldo4, int nnodes)
{
  const int n = blockIdx.x * 4 + (threadIdx.x >> 6);
  if (n >= nnodes) return;
  const int lane = threadIdx.x & 63, l5 = lane & 31, h = lane >> 5;
  const float M = Mp[0], inv = Ip[0];
  float4 av = make_float4(0.f, 0.f, 0.f, 0.f);
  const int p0 = rowstart[n], p1 = rowstart[n+1];
  const int last = p1 - 1;
  for (int p = p0; p < p1; p += 16){
    int idx[8], cc[8]; float aa[8];
    #pragma unroll
    for (int k = 0; k < 8; k++){
      idx[k] = p + 2*k + h;
      const int eff = idx[k] < p1 ? idx[k] : last;
      cc[k] = csrcol[eff];
      aa[k] = sc[eff];
    }
    half4v vv[8];
    #pragma unroll
    for (int k = 0; k < 8; k++) vv[k] = *(const half4v*)(Vh + (unsigned)cc[k]*FD + 4*l5);
    #pragma unroll
    for (int k = 0; k < 8; k++){
      const float m = idx[k] < p1 ? 1.f : 0.f;
      const float a = m * __expf(aa[k] - M);
      av.x += a*(float)vv[k][0]; av.y += a*(float)vv[k][1];
      av.z += a*(float)vv[k][2]; av.w += a*(float)vv[k][3];
    }
  }
  av.x += __shfl_xor(av.x, 32, 64); av.y += __shfl_xor(av.y, 32, 64);
  av.z += __shfl_xor(av.z, 32, 64); av.w += __shfl_xor(av.w, 32, 64);
  if (h == 0)
    out4[(unsigned)n * ldo4 + l5] = make_float4(av.x*inv, av.y*inv, av.z*inv, av.w*inv);
}

// ---------------- fused online softmax reductions ----------------
__global__ __launch_bounds__(256) void k_sm_partial(const float* __restrict__ s, int n,
    float* __restrict__ pm, float* __restrict__ ps){
  __shared__ float sm_m[256], sm_s[256];
  const int tid = threadIdx.x;
  float m = -3.402823466e38f, sum = 0.f;
  for (int i = blockIdx.x * 256 + tid; i < n; i += gridDim.x * 256){
    float v = s[i];
    if (v <= m) sum += __expf(v - m);
    else { sum = sum * __expf(m - v) + 1.f; m = v; }
  }
  sm_m[tid] = m; sm_s[tid] = sum; __syncthreads();
  for (int off = 128; off > 0; off >>= 1){
    if (tid < off){
      float m2 = sm_m[tid + off], s2 = sm_s[tid + off];
      float m1 = sm_m[tid], s1 = sm_s[tid];
      float Mx = fmaxf(m1, m2);
      sm_m[tid] = Mx;
      sm_s[tid] = s1 * __expf(m1 - Mx) + s2 * __expf(m2 - Mx);
    }
    __syncthreads();
  }
  if (tid == 0){ pm[blockIdx.x] = sm_m[0]; ps[blockIdx.x] = sm_s[0]; }
}

__global__ __launch_bounds__(256) void k_sm_final(const float* __restrict__ pm, const float* __restrict__ ps,
    int n, float* __restrict__ Mout, float* __restrict__ Iout){
  __shared__ float sm_m[256], sm_s[256];
  const int tid = threadIdx.x;
  float m = -3.402823466e38f, sum = 0.f;
  for (int i = tid; i < n; i += 256){
    float m2 = pm[i], s2 = ps[i];
    float Mx = fmaxf(m, m2);
    sum = sum * __expf(m - Mx) + s2 * __expf(m2 - Mx);
    m = Mx;
  }
  sm_m[tid] = m; sm_s[tid] = sum; __syncthreads();
  for (int off = 128; off > 0; off >>= 1){
    if (tid < off){
      float m2 = sm_m[tid + off], s2 = sm_s[tid + off];
      float m1 = sm_m[tid], s1 = sm_s[tid];
      float Mx = fmaxf(m1, m2);
      sm_m[tid] = Mx;
      sm_s[tid] = s1 * __expf(m1 - Mx) + s2 * __expf(m2 - Mx);
    }
    __syncthreads();
  }
  if (tid == 0){ Mout[0] = sm_m[0]; Iout[0] = 1.f / sm_s[0]; }
}

extern "C" void kernel_launch(void* const* d_in, const int* in_sizes, int n_in,
                              void* d_out, int out_size, void* d_ws, size_t ws_size,
                              hipStream_t stream)
{
  const float* x   = (const float*)d_in[0];
  const int*   ei  = (const int*)d_in[1];
  const float* Wq1 = (const float*)d_in[2];  const float* bq1 = (const float*)d_in[3];
  const float* Wk1 = (const float*)d_in[4];  const float* bk1 = (const float*)d_in[5];
  const float* Wv1 = (const float*)d_in[6];  const float* bv1 = (const float*)d_in[7];
  const float* Wq2 = (const float*)d_in[8];  const float* bq2 = (const float*)d_in[9];
  const float* Wk2 = (const float*)d_in[10]; const float* bk2 = (const float*)d_in[11];
  const float* Wv2 = (const float*)d_in[12]; const float* bv2 = (const float*)d_in[13];
  const float* Ws1 = (const float*)d_in[14]; const float* bs1 = (const float*)d_in[15];
  const float* Ws2 = (const float*)d_in[16]; const float* bs2 = (const float*)d_in[17];

  const int N = in_sizes[0] / FD;
  const int E = in_sizes[1] / 2;
  const int* row = ei;
  const int* col = ei + E;
  float* out = (float*)d_out;

  char* ws = (char*)d_ws;
  size_t off = 0;
  auto alloc = [&](size_t bytes) -> void* {
    void* p = ws + off;
    off += (bytes + 255) & ~(size_t)255;
    return p;
  };
  int* deg      = (int*)alloc((size_t)N * 4);
  int* rowstart = (int*)alloc((size_t)(N + 1) * 4);
  int* cursor   = (int*)alloc((size_t)N * 4);
  int* csrcol   = (int*)alloc((size_t)E * 4);
  float* scores = (float*)alloc((size_t)E * 4);
  int* blksum   = (int*)alloc(1024);
  int* blkoff   = (int*)alloc(1024);
  float* pm     = (float*)alloc(1024);
  float* ps     = (float*)alloc(1024);
  float* Mv     = (float*)alloc(256);
  float* Iv     = (float*)alloc(256);
  _Float16* Xh = (_Float16*)alloc((size_t)N * FD * 2);   // x fp16; aliased as Sh after passA
  _Float16* Qh = (_Float16*)alloc((size_t)N * FD * 2);
  _Float16* Kh = (_Float16*)alloc((size_t)N * FD * 2);
  _Float16* Vh = (_Float16*)alloc((size_t)N * FD * 2);
  _Float16* Ah = (_Float16*)alloc((size_t)N * FD * 2);
  _Float16* Wh = (_Float16*)alloc((size_t)8 * FD * FD * 2);
  _Float16* Sh = Xh;                 // s1: Xh dead after passA (QKV1 + passA both done)
  _Float16* SMBh = (_Float16*)out;   // seg-mean scratch inside out cols[0,128) bytes, ld 512 halfs
  (void)ws_size; (void)n_in; (void)out_size;

  hipMemsetAsync(deg, 0, (size_t)N * 4, stream);
  hipMemsetAsync(cursor, 0, (size_t)N * 4, stream);

  // conversions
  k_cvt_x<<<2048, 256, 0, stream>>>((const float4*)x, (half4v*)Xh, N * FD / 4);
  k_cvt_w<<<(FD*FD + 255)/256, 256, 0, stream>>>(Wq1, Wk1, Wv1, Wq2, Wk2, Wv2, Ws1, Ws2, Wh);

  // CSR
  const int eb = 2048;
  const int nblk = (N + 1023) / 1024;
  k_count_deg<<<eb, 256, 0, stream>>>(row, E, deg);
  k_scan_blk<<<nblk, 256, 0, stream>>>(deg, N, rowstart, blksum);
  k_scan_part<<<1, 256, 0, stream>>>(blksum, nblk, blkoff);
  k_scan_add<<<(N + 255)/256, 256, 0, stream>>>(rowstart, N, blkoff, E);
  k_fill_csr<<<eb, 256, 0, stream>>>(row, col, E, rowstart, cursor, csrcol);

  const int gb = (N + 63) / 64;
  const int nb = (N + 3) / 4;
  const int rb = 256;

  // ---- layer-1 QKV (LDS-staged MFMA f16, 3 outputs) ----
  k_gemm_lds<3,0,0><<<gb, 256, 0, stream>>>(Xh, FD, Wh + 0*FD*FD,
      bq1, Qh, bk1, Kh, bv1, Vh, FD, N);

  // ---- fused: scores1 + seg_mean(Xh) -> SMBh (fp16 in out, ld 512) ----
  k_passA<<<nb, 256, 0, stream>>>(Qh, Kh, Xh, rowstart, csrcol, scores, SMBh, 512, N);

  k_sm_partial<<<rb, 256, 0, stream>>>(scores, E, pm, ps);
  k_sm_final<<<1, 256, 0, stream>>>(pm, ps, rb, Mv, Iv);

  // s1 = relu(SMBh @ Ws1^T + bs1) -> Sh (fp16 packed; overwrites dead Xh)
  k_gemm_lds<1,1,0><<<gb, 256, 0, stream>>>(SMBh, 512, Wh + 6*FD*FD,
      bs1, Sh, nullptr, nullptr, nullptr, nullptr, FD, N);

  // ---- fused: message1+ELU -> Ah; seg_mean(s1) -> Bh (= SMBh region, SM dead) ----
  k_passB<<<nb, 256, 0, stream>>>(Vh, Sh, scores, Mv, Iv, rowstart, csrcol, Ah, SMBh, 512, N);

  // ss_out = relu(Bh @ Ws2^T + bs2) -> out cols [128,256) fp32
  k_gemm_lds<1,1,1><<<gb, 256, 0, stream>>>(SMBh, 512, Wh + 7*FD*FD,
      bs2, out + FD, nullptr, nullptr, nullptr, nullptr, 2*FD, N);

  // ---- layer-2 QKV (overwrites Qh/Kh/Vh after passB consumed Vh) ----
  k_gemm_lds<3,0,0><<<gb, 256, 0, stream>>>(Ah, FD, Wh + 3*FD*FD,
      bq2, Qh, bk2, Kh, bv2, Vh, FD, N);
  k_scores2<<<nb, 256, 0, stream>>>(Qh, Kh, rowstart, csrcol, scores, N);

  k_sm_partial<<<rb, 256, 0, stream>>>(scores, E, pm, ps);
  k_sm_final<<<1, 256, 0, stream>>>(pm, ps, rb, Mv, Iv);

  // message2 -> out cols [0,128) fp32 (overwrites SMBh region only after GEMM2 consumed it)
  k_message2<<<nb, 256, 0, stream>>>(Vh, scores, Mv, Iv, rowstart, csrcol, (float4*)out, 64, N);
}